// Round 3
// baseline (255.671 us; speedup 1.0000x reference)
//
#include <hip/hip_runtime.h>

typedef unsigned long long u64;

// Dims: b=8, N=1024, L=4, C=128, O=64, F=64, C+O=192
// All float tensors are FP32 (reference dtype). Output: [8*1024*64] out, then [8*64] gs_out.
// ---------------------------------------------------------------------------
// k_gs: gs = global_state@Wg (f32, ws), gs BN+relu -> out_gs,
//       wa1/wa2[l][c] = sum_f W[l][c][f]*a{1,2}[l][f]
__global__ __launch_bounds__(512)
void k_gs(const float* gstate, const float* Wg, const float* W, const float* a1, const float* a2,
          const float* gamma_g, const float* beta_g, float* gs, float* wa1, float* wa2, float* outg)
{
    int t = threadIdx.x;
    int b = t >> 6, o = t & 63;
    float acc = 0.f;
    for (int c = 0; c < 128; ++c)
        acc += gstate[b*128 + c] * Wg[c*64 + o];
    __shared__ float sgs[512];
    __shared__ float mu_s[64], rs_s[64];
    sgs[t] = acc; gs[t] = acc;
    __syncthreads();
    if (t < 64) {
        float s = 0.f, sq = 0.f;
        for (int bb = 0; bb < 8; ++bb) { float v = sgs[bb*64 + t]; s += v; sq += v*v; }
        float mu = s * 0.125f;
        float var = sq * 0.125f - mu*mu;
        mu_s[t] = mu; rs_s[t] = rsqrtf(var + 1e-5f);
    }
    __syncthreads();
    {
        float v = (sgs[t] - mu_s[o]) * rs_s[o] * gamma_g[o] + beta_g[o];
        outg[t] = fmaxf(v, 0.f);
    }
    for (int e = t; e < 768; e += 512) {
        int l = e / 192, c = e - l*192;
        float s1 = 0.f, s2 = 0.f;
        const float* wp = W + (l*192 + c) * 64;
        for (int f = 0; f < 64; ++f) {
            float w = wp[f];
            s1 += w * a1[l*64 + f];
            s2 += w * a2[l*64 + f];
        }
        wa1[e] = s1; wa2[e] = s2;
    }
}

// ---------------------------------------------------------------------------
// k_h: h[l][b][n][f] (f32) = Vg[b,n,:] @ W[l];  f1/f2[l][b][n] = Vg . wa{1,2}[l]
// grid 256 = (b=8) x (nt=32 tiles of 32 rows); block 256
__global__ __launch_bounds__(256)
void k_h(const float* V, const int* gsize, const float* gs, const float* W,
         const float* wa1, const float* wa2, float* h, float* f1, float* f2)
{
    int blk = blockIdx.x;
    int b = blk >> 5, nt = blk & 31, n0 = nt * 32;
    int t = threadIdx.x;
    __shared__ float vg[32][194];   // pad 194
    {
        int r = t >> 3, c0 = (t & 7) * 16;
        const float* vp = V + ((size_t)(b*1024 + n0 + r) * 128 + c0);
        float4 v0 = *(const float4*)(vp + 0);
        float4 v1 = *(const float4*)(vp + 4);
        float4 v2 = *(const float4*)(vp + 8);
        float4 v3 = *(const float4*)(vp + 12);
        *(float4*)&vg[r][c0 + 0]  = v0;
        *(float4*)&vg[r][c0 + 4]  = v1;
        *(float4*)&vg[r][c0 + 8]  = v2;
        *(float4*)&vg[r][c0 + 12] = v3;
    }
    {
        int r = t >> 3, o0 = (t & 7) * 8;
        bool on = (n0 + r) < gsize[b];
        for (int j = 0; j < 8; ++j) vg[r][128 + o0 + j] = on ? gs[b*64 + o0 + j] : 0.f;
    }
    __syncthreads();
    int ty = t >> 5, tx = t & 31;
    int r0 = ty * 4;
    int j0 = tx * 8;
    int lw = j0 >> 6, f0 = j0 & 63;
    float acc[4][8];
    for (int i = 0; i < 4; ++i) for (int j = 0; j < 8; ++j) acc[i][j] = 0.f;
    const float* wp = W + (size_t)(lw*192) * 64 + f0;
    for (int c = 0; c < 192; ++c) {
        float4 wl = *(const float4*)(wp + c*64);
        float4 wh = *(const float4*)(wp + c*64 + 4);
        float wf[8] = {wl.x, wl.y, wl.z, wl.w, wh.x, wh.y, wh.z, wh.w};
        float a0 = vg[r0+0][c], a1v = vg[r0+1][c], a2v = vg[r0+2][c], a3v = vg[r0+3][c];
        for (int j = 0; j < 8; ++j) {
            acc[0][j] += a0  * wf[j];
            acc[1][j] += a1v * wf[j];
            acc[2][j] += a2v * wf[j];
            acc[3][j] += a3v * wf[j];
        }
    }
    for (int i = 0; i < 4; ++i) {
        int n = n0 + r0 + i;
        float* hp = h + ((size_t)(lw*8 + b) * 1024 + n) * 64 + f0;
        *(float4*)(hp + 0) = make_float4(acc[i][0], acc[i][1], acc[i][2], acc[i][3]);
        *(float4*)(hp + 4) = make_float4(acc[i][4], acc[i][5], acc[i][6], acc[i][7]);
    }
    // f1/f2: 32 rows x 4 l x 2 = 256 items
    {
        int r = t & 31, l = (t >> 5) & 3, which = t >> 7;
        const float* wl = (which ? wa2 : wa1) + l*192;
        float s = 0.f;
        for (int c = 0; c < 192; ++c) s += vg[r][c] * wl[c];
        float* dst = which ? f2 : f1;
        dst[(l*8 + b) * 1024 + n0 + r] = s;
    }
}

// ---------------------------------------------------------------------------
// k_stats: per-column (softmax over n) online max/sum partials + ballot-packed mask
// grid 512 = l(4) x b(8) x mc(4: 256 cols) x nc(4: 256 rows); block 256 (1 col/thread)
__global__ __launch_bounds__(256)
void k_stats(const float* A, const float* f1, const float* f2, u64* maskp, float* pmax, float* psum)
{
    int blk = blockIdx.x;
    int l = blk >> 7, b = (blk >> 4) & 7, mc = (blk >> 2) & 3, nc = blk & 3;
    int t = threadIdx.x;
    int m = mc*256 + t;
    int lb = l*8 + b;
    int lbm = lb*1024 + m;
    float f2v = f2[lbm];
    float mx = -3.0e38f, s = 0.f;
    const float* Ap = A + ((size_t)(b*1024 + nc*256) * 4 + l) * 1024 + m;
    const float* f1p = f1 + lb*1024 + nc*256;
    int wid = t >> 6;
    bool lead = (t & 63) == 0;
    for (int n = 0; n < 256; ++n) {
        float a = Ap[(size_t)n * 4096];
        bool pos = a > 0.f;
        u64 bal = __ballot(pos);
        if (lead) maskp[((size_t)(b*1024 + nc*256 + n) * 4 + l) * 16 + mc*4 + wid] = bal;
        float e = f1p[n] + f2v;
        e = e > 0.f ? e : 0.2f * e;       // leaky_relu(0.2)
        float v = pos ? e : -9e15f;       // NEG fill
        float nm = fmaxf(mx, v);
        s = s * __expf(mx - nm) + __expf(v - nm);
        mx = nm;
    }
    pmax[nc*32768 + lbm] = mx;
    psum[nc*32768 + lbm] = s;
}

// ---------------------------------------------------------------------------
__global__ __launch_bounds__(256)
void k_combine(const float* pmax, const float* psum, float* colmax, float* rcolsum)
{
    int i = blockIdx.x * 256 + threadIdx.x;
    float m0 = pmax[i], m1 = pmax[32768 + i], m2 = pmax[65536 + i], m3 = pmax[98304 + i];
    float mx = fmaxf(fmaxf(m0, m1), fmaxf(m2, m3));
    float s = psum[i]         * __expf(m0 - mx) + psum[32768 + i] * __expf(m1 - mx)
            + psum[65536 + i] * __expf(m2 - mx) + psum[98304 + i] * __expf(m3 - mx);
    colmax[i] = mx;
    rcolsum[i] = 1.f / s;
}

// ---------------------------------------------------------------------------
// k_pass2: outl[l][b][n][f] = sum_m att[l,b,n,m] * h[l,b,m,f]
// grid 512 = l(4) x b(8) x nt(16 tiles of 64 rows); block 256; C-tile 64x64, 4x4/thread
__global__ __launch_bounds__(256)
void k_pass2(const float* h, const u64* maskp, const float* f1, const float* f2,
             const float* colmax, const float* rcolsum, float* outl)
{
    int blk = blockIdx.x;
    int l = blk >> 7, b = (blk >> 4) & 7, nt = blk & 15, n0 = nt * 64;
    int lb = l*8 + b;
    int t = threadIdx.x;
    __shared__ float att[64][68];
    __shared__ float hl[64][68];
    int ty = t >> 4, tx = t & 15;
    int r0 = ty * 4, f0 = tx * 4;
    int rs_ = t >> 2;                // staging row (0..63)
    int mo = (t & 3) * 16;           // staging col offset within 64-chunk
    float f1v = f1[lb*1024 + n0 + rs_];
    size_t mwbase = ((size_t)(b*1024 + n0 + rs_) * 4 + l) * 16;
    int hrow = t >> 2, fo = (t & 3) * 16;
    float acc[4][4];
    for (int i = 0; i < 4; ++i) for (int j = 0; j < 4; ++j) acc[i][j] = 0.f;

    for (int mc = 0; mc < 16; ++mc) {
        {   // att staging: att = exp(v - colmax) * rcolsum; v = maskbit ? leaky(f1+f2) : NEG
            u64 w = maskp[mwbase + mc] >> mo;
            int mbase = lb*1024 + mc*64 + mo;
            for (int j = 0; j < 16; ++j) {
                float cm = colmax[mbase + j];
                float rsum = rcolsum[mbase + j];
                float e = f1v + f2[mbase + j];
                e = e > 0.f ? e : 0.2f * e;
                float v = ((w >> j) & 1) ? e : -9e15f;
                att[rs_][mo + j] = __expf(v - cm) * rsum;
            }
        }
        {   // h staging (f32)
            const float* hp = h + ((size_t)(lb*1024 + mc*64 + hrow)) * 64 + fo;
            float4 v0 = *(const float4*)(hp + 0);
            float4 v1 = *(const float4*)(hp + 4);
            float4 v2 = *(const float4*)(hp + 8);
            float4 v3 = *(const float4*)(hp + 12);
            *(float4*)&hl[hrow][fo + 0]  = v0;
            *(float4*)&hl[hrow][fo + 4]  = v1;
            *(float4*)&hl[hrow][fo + 8]  = v2;
            *(float4*)&hl[hrow][fo + 12] = v3;
        }
        __syncthreads();
        #pragma unroll 4
        for (int mm = 0; mm < 64; mm += 4) {
            float4 A0 = *(const float4*)&att[r0+0][mm];
            float4 A1 = *(const float4*)&att[r0+1][mm];
            float4 A2 = *(const float4*)&att[r0+2][mm];
            float4 A3 = *(const float4*)&att[r0+3][mm];
            float4 H0 = *(const float4*)&hl[mm+0][f0];
            float4 H1 = *(const float4*)&hl[mm+1][f0];
            float4 H2 = *(const float4*)&hl[mm+2][f0];
            float4 H3 = *(const float4*)&hl[mm+3][f0];
            #define UPD(ai, Ai)                                              \
                acc[ai][0] += Ai.x*H0.x + Ai.y*H1.x + Ai.z*H2.x + Ai.w*H3.x; \
                acc[ai][1] += Ai.x*H0.y + Ai.y*H1.y + Ai.z*H2.y + Ai.w*H3.y; \
                acc[ai][2] += Ai.x*H0.z + Ai.y*H1.z + Ai.z*H2.z + Ai.w*H3.z; \
                acc[ai][3] += Ai.x*H0.w + Ai.y*H1.w + Ai.z*H2.w + Ai.w*H3.w;
            UPD(0, A0) UPD(1, A1) UPD(2, A2) UPD(3, A3)
            #undef UPD
        }
        __syncthreads();
    }
    for (int i = 0; i < 4; ++i) {
        *(float4*)(outl + ((size_t)lb*1024 + n0 + r0 + i) * 64 + f0)
            = make_float4(acc[i][0], acc[i][1], acc[i][2], acc[i][3]);
    }
}

// ---------------------------------------------------------------------------
// k_reduce: outpre = sum_l outl + bias; per-f BN partial sums via LDS + global atomics
// grid 128 (outpre = 524288 floats, 4096 per block); l-stride in outl = 524288 floats
// NOTE: outpre may alias outl's l=0 slice — each element is read (v0) before being
// overwritten by the same thread, and no other thread touches it.
__global__ __launch_bounds__(256)
void k_reduce(const float* outl, const float* bias, float* outpre, float* bnsum, float* bnsumsq)
{
    int blk = blockIdx.x, t = threadIdx.x;
    __shared__ float red[2][64];
    if (t < 128) red[t >> 6][t & 63] = 0.f;
    __syncthreads();
    int f0 = (t * 4) & 63;
    float bs[4];
    for (int j = 0; j < 4; ++j) bs[j] = bias[f0 + j];
    float s[4] = {0,0,0,0}, sq[4] = {0,0,0,0};
    for (int g = 0; g < 4; ++g) {
        size_t base = (size_t)blk * 4096 + g * 1024 + t * 4;
        float4 v0 = *(const float4*)(outl + base);
        float4 v1 = *(const float4*)(outl + 524288 + base);
        float4 v2 = *(const float4*)(outl + 1048576 + base);
        float4 v3 = *(const float4*)(outl + 1572864 + base);
        float o[4] = { v0.x + v1.x + v2.x + v3.x + bs[0],
                       v0.y + v1.y + v2.y + v3.y + bs[1],
                       v0.z + v1.z + v2.z + v3.z + bs[2],
                       v0.w + v1.w + v2.w + v3.w + bs[3] };
        *(float4*)(outpre + base) = make_float4(o[0], o[1], o[2], o[3]);
        for (int j = 0; j < 4; ++j) { s[j] += o[j]; sq[j] += o[j]*o[j]; }
    }
    for (int j = 0; j < 4; ++j) {
        atomicAdd(&red[0][f0 + j], s[j]);
        atomicAdd(&red[1][f0 + j], sq[j]);
    }
    __syncthreads();
    if (t < 64) { atomicAdd(&bnsum[t], red[0][t]); atomicAdd(&bnsumsq[t], red[1][t]); }
}

// ---------------------------------------------------------------------------
// grid 128 (covers exactly 524288 output elems)
__global__ __launch_bounds__(256)
void k_bnapply(const float* outpre, const float* bnsum, const float* bnsumsq,
               const float* gamma, const float* beta, float* out)
{
    int blk = blockIdx.x, t = threadIdx.x;
    int f0 = (t * 4) & 63;
    float mu[4], rstd[4], ga[4], be[4];
    for (int j = 0; j < 4; ++j) {
        float sm = bnsum[f0 + j], sq = bnsumsq[f0 + j];
        float m = sm * (1.f / 8192.f);
        float var = sq * (1.f / 8192.f) - m*m;
        mu[j] = m; rstd[j] = rsqrtf(var + 1e-5f);
        ga[j] = gamma[f0 + j]; be[j] = beta[f0 + j];
    }
    for (int g = 0; g < 4; ++g) {
        size_t base = (size_t)blk * 4096 + g * 1024 + t * 4;
        float4 v = *(const float4*)(outpre + base);
        float x[4] = {v.x, v.y, v.z, v.w};
        float y[4];
        for (int j = 0; j < 4; ++j) {
            float z = (x[j] - mu[j]) * rstd[j] * ga[j] + be[j];
            y[j] = fmaxf(z, 0.f);
        }
        *(float4*)(out + base) = make_float4(y[0], y[1], y[2], y[3]);
    }
}

// ---------------------------------------------------------------------------
extern "C" void kernel_launch(void* const* d_in, const int* in_sizes, int n_in,
                              void* d_out, int out_size, void* d_ws, size_t ws_size,
                              hipStream_t stream)
{
    const float* V       = (const float*)d_in[0];
    const float* A       = (const float*)d_in[1];
    const float* gstate  = (const float*)d_in[2];
    const int*   gsize   = (const int*)d_in[3];
    // d_in[4] subgraph_size: unused by reference
    const float* Wg      = (const float*)d_in[5];
    const float* W       = (const float*)d_in[6];
    const float* a1      = (const float*)d_in[7];
    const float* a2      = (const float*)d_in[8];
    const float* bias    = (const float*)d_in[9];
    const float* gamma_n = (const float*)d_in[10];
    const float* beta_n  = (const float*)d_in[11];
    const float* gamma_g = (const float*)d_in[12];
    const float* beta_g  = (const float*)d_in[13];

    char* ws = (char*)d_ws;               // ~22.6 MB used
    float* gs      = (float*)(ws + 0);
    float* wa1     = (float*)(ws + 2048);
    float* wa2     = (float*)(ws + 5120);
    float* f1      = (float*)(ws + 8192);
    float* f2      = (float*)(ws + 139264);
    float* pmax    = (float*)(ws + 270336);
    float* psum    = (float*)(ws + 794624);
    float* colmax  = (float*)(ws + 1318912);
    float* rcolsum = (float*)(ws + 1449984);
    float* bnsum   = (float*)(ws + 1581056);
    float* bnsumsq = (float*)(ws + 1581312);
    u64*   maskp   = (u64*)  (ws + 1581568);   // 4 MB
    float* h       = (float*)(ws + 5775872);   // 8 MB (f32 now)
    float* outl    = (float*)(ws + 14164480);  // 8 MB
    float* outpre  = outl;                     // alias l=0 slice (safe, see k_reduce)

    float* out_main = (float*)d_out;
    float* out_gs   = out_main + 524288;

    hipMemsetAsync(bnsum, 0, 512, stream);   // bnsum + bnsumsq
    hipLaunchKernelGGL(k_gs,      dim3(1),   dim3(512), 0, stream,
                       gstate, Wg, W, a1, a2, gamma_g, beta_g, gs, wa1, wa2, out_gs);
    hipLaunchKernelGGL(k_h,       dim3(256), dim3(256), 0, stream,
                       V, gsize, gs, W, wa1, wa2, h, f1, f2);
    hipLaunchKernelGGL(k_stats,   dim3(512), dim3(256), 0, stream,
                       A, f1, f2, maskp, pmax, psum);
    hipLaunchKernelGGL(k_combine, dim3(128), dim3(256), 0, stream,
                       pmax, psum, colmax, rcolsum);
    hipLaunchKernelGGL(k_pass2,   dim3(512), dim3(256), 0, stream,
                       h, maskp, f1, f2, colmax, rcolsum, outl);
    hipLaunchKernelGGL(k_reduce,  dim3(128), dim3(256), 0, stream,
                       outl, bias, outpre, bnsum, bnsumsq);
    hipLaunchKernelGGL(k_bnapply, dim3(128), dim3(256), 0, stream,
                       outpre, bnsum, bnsumsq, gamma_n, beta_n, out_main);
}

// Round 4
// 229.378 us; speedup vs baseline: 1.1146x; 1.1146x over previous
//
#include <hip/hip_runtime.h>

typedef unsigned long long u64;

// Dims: b=8, N=1024, L=4, C=128, O=64, F=64, C+O=192
// All float tensors are FP32 (reference dtype). Output: [8*1024*64] out, then [8*64] gs_out.
// ---------------------------------------------------------------------------
// k_gs: gs = global_state@Wg (f32, ws), gs BN+relu -> out_gs,
//       wa1/wa2[l][c] = sum_f W[l][c][f]*a{1,2}[l][f]
__global__ __launch_bounds__(512)
void k_gs(const float* gstate, const float* Wg, const float* W, const float* a1, const float* a2,
          const float* gamma_g, const float* beta_g, float* gs, float* wa1, float* wa2, float* outg)
{
    int t = threadIdx.x;
    int b = t >> 6, o = t & 63;
    float acc = 0.f;
    for (int c = 0; c < 128; ++c)
        acc += gstate[b*128 + c] * Wg[c*64 + o];
    __shared__ float sgs[512];
    __shared__ float mu_s[64], rs_s[64];
    sgs[t] = acc; gs[t] = acc;
    __syncthreads();
    if (t < 64) {
        float s = 0.f, sq = 0.f;
        for (int bb = 0; bb < 8; ++bb) { float v = sgs[bb*64 + t]; s += v; sq += v*v; }
        float mu = s * 0.125f;
        float var = sq * 0.125f - mu*mu;
        mu_s[t] = mu; rs_s[t] = rsqrtf(var + 1e-5f);
    }
    __syncthreads();
    {
        float v = (sgs[t] - mu_s[o]) * rs_s[o] * gamma_g[o] + beta_g[o];
        outg[t] = fmaxf(v, 0.f);
    }
    for (int e = t; e < 768; e += 512) {
        int l = e / 192, c = e - l*192;
        float s1 = 0.f, s2 = 0.f;
        const float* wp = W + (l*192 + c) * 64;
        for (int f = 0; f < 64; ++f) {
            float w = wp[f];
            s1 += w * a1[l*64 + f];
            s2 += w * a2[l*64 + f];
        }
        wa1[e] = s1; wa2[e] = s2;
    }
}

// ---------------------------------------------------------------------------
// k_h: h[l][b][n][f] (f32) = Vg[b,n,:] @ W[l];  f1/f2[l][b][n] = Vg . wa{1,2}[l]
// grid 256 = (b=8) x (nt=32 tiles of 32 rows); block 256
__global__ __launch_bounds__(256)
void k_h(const float* V, const int* gsize, const float* gs, const float* W,
         const float* wa1, const float* wa2, float* h, float* f1, float* f2)
{
    int blk = blockIdx.x;
    int b = blk >> 5, nt = blk & 31, n0 = nt * 32;
    int t = threadIdx.x;
    __shared__ float vg[32][194];   // pad 194
    {
        int r = t >> 3, c0 = (t & 7) * 16;
        const float* vp = V + ((size_t)(b*1024 + n0 + r) * 128 + c0);
        float4 v0 = *(const float4*)(vp + 0);
        float4 v1 = *(const float4*)(vp + 4);
        float4 v2 = *(const float4*)(vp + 8);
        float4 v3 = *(const float4*)(vp + 12);
        *(float4*)&vg[r][c0 + 0]  = v0;
        *(float4*)&vg[r][c0 + 4]  = v1;
        *(float4*)&vg[r][c0 + 8]  = v2;
        *(float4*)&vg[r][c0 + 12] = v3;
    }
    {
        int r = t >> 3, o0 = (t & 7) * 8;
        bool on = (n0 + r) < gsize[b];
        for (int j = 0; j < 8; ++j) vg[r][128 + o0 + j] = on ? gs[b*64 + o0 + j] : 0.f;
    }
    __syncthreads();
    int ty = t >> 5, tx = t & 31;
    int r0 = ty * 4;
    int j0 = tx * 8;
    int lw = j0 >> 6, f0 = j0 & 63;
    float acc[4][8];
    for (int i = 0; i < 4; ++i) for (int j = 0; j < 8; ++j) acc[i][j] = 0.f;
    const float* wp = W + (size_t)(lw*192) * 64 + f0;
    for (int c = 0; c < 192; ++c) {
        float4 wl = *(const float4*)(wp + c*64);
        float4 wh = *(const float4*)(wp + c*64 + 4);
        float wf[8] = {wl.x, wl.y, wl.z, wl.w, wh.x, wh.y, wh.z, wh.w};
        float a0 = vg[r0+0][c], a1v = vg[r0+1][c], a2v = vg[r0+2][c], a3v = vg[r0+3][c];
        for (int j = 0; j < 8; ++j) {
            acc[0][j] += a0  * wf[j];
            acc[1][j] += a1v * wf[j];
            acc[2][j] += a2v * wf[j];
            acc[3][j] += a3v * wf[j];
        }
    }
    for (int i = 0; i < 4; ++i) {
        int n = n0 + r0 + i;
        float* hp = h + ((size_t)(lw*8 + b) * 1024 + n) * 64 + f0;
        *(float4*)(hp + 0) = make_float4(acc[i][0], acc[i][1], acc[i][2], acc[i][3]);
        *(float4*)(hp + 4) = make_float4(acc[i][4], acc[i][5], acc[i][6], acc[i][7]);
    }
    // f1/f2: 32 rows x 4 l x 2 = 256 items
    {
        int r = t & 31, l = (t >> 5) & 3, which = t >> 7;
        const float* wl = (which ? wa2 : wa1) + l*192;
        float s = 0.f;
        for (int c = 0; c < 192; ++c) s += vg[r][c] * wl[c];
        float* dst = which ? f2 : f1;
        dst[(l*8 + b) * 1024 + n0 + r] = s;
    }
}

// ---------------------------------------------------------------------------
// k_mask_max: stream A once -> ballot-packed mask bits AND per-column partial
// max of masked f1 (leaky is monotone, so colmax = leaky(f2 + max masked f1)).
// grid 1024 = b(8) x l(4) x nc(8: 128-row chunks) x wg(4); block 256 (4 waves, w = wg*4+wv)
__global__ __launch_bounds__(256)
void k_mask_max(const float* A, const float* f1, u64* maskp, float* pmaxf1)
{
    int blk = blockIdx.x;
    int wg = blk & 3, nc = (blk >> 2) & 7, l = (blk >> 5) & 3, b = blk >> 7;
    int t = threadIdx.x;
    int wv = t >> 6, lane = t & 63;
    int w = wg*4 + wv;
    int m = w*64 + lane;
    int n0 = nc*128;
    int lb = l*8 + b;
    __shared__ float f1s[128];
    if (t < 128) f1s[t] = f1[lb*1024 + n0 + t];
    __syncthreads();
    float mx = -3.0e38f;
    const float* Ap = A + (((size_t)(b*1024 + n0) * 4 + l) * 1024 + m);
    u64* mp = maskp + ((size_t)(b*1024 + n0) * 4 + l) * 16 + w;
    #pragma unroll 4
    for (int n = 0; n < 128; ++n) {
        float a = Ap[(size_t)n * 4096];
        bool pos = a > 0.f;
        u64 bal = __ballot(pos);
        if (lane == 0) mp[(size_t)n * 64] = bal;
        if (pos) mx = fmaxf(mx, f1s[n]);
    }
    pmaxf1[nc*32768 + lb*1024 + m] = mx;
}

// ---------------------------------------------------------------------------
// k_cmax: colmax[lbm] = empty ? NEG : leaky(f2 + max over 8 partials)
__global__ __launch_bounds__(256)
void k_cmax(const float* pmaxf1, const float* f2, float* colmax)
{
    int i = blockIdx.x * 256 + threadIdx.x;   // 32768
    float mx = pmaxf1[i];
    for (int k = 1; k < 8; ++k) mx = fmaxf(mx, pmaxf1[k*32768 + i]);
    float e = f2[i] + mx;
    e = e > 0.f ? e : 0.2f * e;
    colmax[i] = (mx < -1e38f) ? -9e15f : e;
}

// ---------------------------------------------------------------------------
// k_colsum: partial denominators: psum[nc][lbm] = sum_n exp((mask? e : NEG) - colmax)
// grid 512 = l(4) x b(8) x mc(4: 256 cols) x nc(4: 256 rows); block 256 (1 col/thread)
__global__ __launch_bounds__(256)
void k_colsum(const u64* maskp, const float* f1, const float* f2, const float* colmax, float* psum)
{
    int blk = blockIdx.x;
    int nc = blk & 3, mc = (blk >> 2) & 3, b = (blk >> 4) & 7, l = blk >> 7;
    int t = threadIdx.x;
    int lb = l*8 + b;
    int m = mc*256 + t;
    int n0 = nc*256;
    __shared__ float f1s[256];
    __shared__ u64 wlds[1024];
    f1s[t] = f1[lb*1024 + n0 + t];
    for (int k = 0; k < 4; ++k) {
        int e = t + k*256;
        int n = e >> 2, ws_ = e & 3;
        wlds[e] = maskp[((size_t)(b*1024 + n0 + n) * 4 + l) * 16 + mc*4 + ws_];
    }
    __syncthreads();
    float f2v = f2[lb*1024 + m];
    float cm  = colmax[lb*1024 + m];
    int wv = t >> 6;
    int bit = t & 63;
    float s = 0.f;
    #pragma unroll 4
    for (int n = 0; n < 256; ++n) {
        u64 word = wlds[n*4 + wv];
        float e1 = f1s[n] + f2v;
        e1 = e1 > 0.f ? e1 : 0.2f * e1;
        float v = ((word >> bit) & 1) ? e1 : -9e15f;
        s += __expf(v - cm);
    }
    psum[nc*32768 + lb*1024 + m] = s;
}

// ---------------------------------------------------------------------------
__global__ __launch_bounds__(256)
void k_csum(const float* psum, float* rcolsum)
{
    int i = blockIdx.x * 256 + threadIdx.x;
    float s = psum[i] + psum[32768 + i] + psum[65536 + i] + psum[98304 + i];
    rcolsum[i] = 1.f / s;
}

// ---------------------------------------------------------------------------
// k_pass2: outl[l][b][n][f] = sum_m att[l,b,n,m] * h[l,b,m,f]
// grid 512 = l(4) x b(8) x nt(16 tiles of 64 rows); block 256; C-tile 64x64, 4x4/thread
__global__ __launch_bounds__(256)
void k_pass2(const float* h, const u64* maskp, const float* f1, const float* f2,
             const float* colmax, const float* rcolsum, float* outl)
{
    int blk = blockIdx.x;
    int l = blk >> 7, b = (blk >> 4) & 7, nt = blk & 15, n0 = nt * 64;
    int lb = l*8 + b;
    int t = threadIdx.x;
    __shared__ float att[64][68];
    __shared__ float hl[64][68];
    int ty = t >> 4, tx = t & 15;
    int r0 = ty * 4, f0 = tx * 4;
    int rs_ = t >> 2;                // staging row (0..63)
    int mo = (t & 3) * 16;           // staging col offset within 64-chunk
    float f1v = f1[lb*1024 + n0 + rs_];
    size_t mwbase = ((size_t)(b*1024 + n0 + rs_) * 4 + l) * 16;
    int hrow = t >> 2, fo = (t & 3) * 16;
    float acc[4][4];
    for (int i = 0; i < 4; ++i) for (int j = 0; j < 4; ++j) acc[i][j] = 0.f;

    for (int mc = 0; mc < 16; ++mc) {
        {   // att staging: att = exp(v - colmax) * rcolsum; v = maskbit ? leaky(f1+f2) : NEG
            u64 w = maskp[mwbase + mc] >> mo;
            int mbase = lb*1024 + mc*64 + mo;
            for (int j = 0; j < 16; ++j) {
                float cm = colmax[mbase + j];
                float rsum = rcolsum[mbase + j];
                float e = f1v + f2[mbase + j];
                e = e > 0.f ? e : 0.2f * e;
                float v = ((w >> j) & 1) ? e : -9e15f;
                att[rs_][mo + j] = __expf(v - cm) * rsum;
            }
        }
        {   // h staging (f32)
            const float* hp = h + ((size_t)(lb*1024 + mc*64 + hrow)) * 64 + fo;
            float4 v0 = *(const float4*)(hp + 0);
            float4 v1 = *(const float4*)(hp + 4);
            float4 v2 = *(const float4*)(hp + 8);
            float4 v3 = *(const float4*)(hp + 12);
            *(float4*)&hl[hrow][fo + 0]  = v0;
            *(float4*)&hl[hrow][fo + 4]  = v1;
            *(float4*)&hl[hrow][fo + 8]  = v2;
            *(float4*)&hl[hrow][fo + 12] = v3;
        }
        __syncthreads();
        #pragma unroll 4
        for (int mm = 0; mm < 64; mm += 4) {
            float4 A0 = *(const float4*)&att[r0+0][mm];
            float4 A1 = *(const float4*)&att[r0+1][mm];
            float4 A2 = *(const float4*)&att[r0+2][mm];
            float4 A3 = *(const float4*)&att[r0+3][mm];
            float4 H0 = *(const float4*)&hl[mm+0][f0];
            float4 H1 = *(const float4*)&hl[mm+1][f0];
            float4 H2 = *(const float4*)&hl[mm+2][f0];
            float4 H3 = *(const float4*)&hl[mm+3][f0];
            #define UPD(ai, Ai)                                              \
                acc[ai][0] += Ai.x*H0.x + Ai.y*H1.x + Ai.z*H2.x + Ai.w*H3.x; \
                acc[ai][1] += Ai.x*H0.y + Ai.y*H1.y + Ai.z*H2.y + Ai.w*H3.y; \
                acc[ai][2] += Ai.x*H0.z + Ai.y*H1.z + Ai.z*H2.z + Ai.w*H3.z; \
                acc[ai][3] += Ai.x*H0.w + Ai.y*H1.w + Ai.z*H2.w + Ai.w*H3.w;
            UPD(0, A0) UPD(1, A1) UPD(2, A2) UPD(3, A3)
            #undef UPD
        }
        __syncthreads();
    }
    for (int i = 0; i < 4; ++i) {
        *(float4*)(outl + ((size_t)lb*1024 + n0 + r0 + i) * 64 + f0)
            = make_float4(acc[i][0], acc[i][1], acc[i][2], acc[i][3]);
    }
}

// ---------------------------------------------------------------------------
// k_reduce: outpre = sum_l outl + bias; per-f BN partial sums via LDS + global atomics
// grid 128 (outpre = 524288 floats, 4096 per block); l-stride in outl = 524288 floats
// NOTE: outpre aliases outl's l=0 slice — each element is read (v0) before being
// overwritten by the same thread, and no other thread touches it.
__global__ __launch_bounds__(256)
void k_reduce(const float* outl, const float* bias, float* outpre, float* bnsum, float* bnsumsq)
{
    int blk = blockIdx.x, t = threadIdx.x;
    __shared__ float red[2][64];
    if (t < 128) red[t >> 6][t & 63] = 0.f;
    __syncthreads();
    int f0 = (t * 4) & 63;
    float bs[4];
    for (int j = 0; j < 4; ++j) bs[j] = bias[f0 + j];
    float s[4] = {0,0,0,0}, sq[4] = {0,0,0,0};
    for (int g = 0; g < 4; ++g) {
        size_t base = (size_t)blk * 4096 + g * 1024 + t * 4;
        float4 v0 = *(const float4*)(outl + base);
        float4 v1 = *(const float4*)(outl + 524288 + base);
        float4 v2 = *(const float4*)(outl + 1048576 + base);
        float4 v3 = *(const float4*)(outl + 1572864 + base);
        float o[4] = { v0.x + v1.x + v2.x + v3.x + bs[0],
                       v0.y + v1.y + v2.y + v3.y + bs[1],
                       v0.z + v1.z + v2.z + v3.z + bs[2],
                       v0.w + v1.w + v2.w + v3.w + bs[3] };
        *(float4*)(outpre + base) = make_float4(o[0], o[1], o[2], o[3]);
        for (int j = 0; j < 4; ++j) { s[j] += o[j]; sq[j] += o[j]*o[j]; }
    }
    for (int j = 0; j < 4; ++j) {
        atomicAdd(&red[0][f0 + j], s[j]);
        atomicAdd(&red[1][f0 + j], sq[j]);
    }
    __syncthreads();
    if (t < 64) { atomicAdd(&bnsum[t], red[0][t]); atomicAdd(&bnsumsq[t], red[1][t]); }
}

// ---------------------------------------------------------------------------
// grid 128 (covers exactly 524288 output elems)
__global__ __launch_bounds__(256)
void k_bnapply(const float* outpre, const float* bnsum, const float* bnsumsq,
               const float* gamma, const float* beta, float* out)
{
    int blk = blockIdx.x, t = threadIdx.x;
    int f0 = (t * 4) & 63;
    float mu[4], rstd[4], ga[4], be[4];
    for (int j = 0; j < 4; ++j) {
        float sm = bnsum[f0 + j], sq = bnsumsq[f0 + j];
        float m = sm * (1.f / 8192.f);
        float var = sq * (1.f / 8192.f) - m*m;
        mu[j] = m; rstd[j] = rsqrtf(var + 1e-5f);
        ga[j] = gamma[f0 + j]; be[j] = beta[f0 + j];
    }
    for (int g = 0; g < 4; ++g) {
        size_t base = (size_t)blk * 4096 + g * 1024 + t * 4;
        float4 v = *(const float4*)(outpre + base);
        float x[4] = {v.x, v.y, v.z, v.w};
        float y[4];
        for (int j = 0; j < 4; ++j) {
            float z = (x[j] - mu[j]) * rstd[j] * ga[j] + be[j];
            y[j] = fmaxf(z, 0.f);
        }
        *(float4*)(out + base) = make_float4(y[0], y[1], y[2], y[3]);
    }
}

// ---------------------------------------------------------------------------
extern "C" void kernel_launch(void* const* d_in, const int* in_sizes, int n_in,
                              void* d_out, int out_size, void* d_ws, size_t ws_size,
                              hipStream_t stream)
{
    const float* V       = (const float*)d_in[0];
    const float* A       = (const float*)d_in[1];
    const float* gstate  = (const float*)d_in[2];
    const int*   gsize   = (const int*)d_in[3];
    // d_in[4] subgraph_size: unused by reference
    const float* Wg      = (const float*)d_in[5];
    const float* W       = (const float*)d_in[6];
    const float* a1      = (const float*)d_in[7];
    const float* a2      = (const float*)d_in[8];
    const float* bias    = (const float*)d_in[9];
    const float* gamma_n = (const float*)d_in[10];
    const float* beta_n  = (const float*)d_in[11];
    const float* gamma_g = (const float*)d_in[12];
    const float* beta_g  = (const float*)d_in[13];

    char* ws = (char*)d_ws;               // ~22.6 MB used (same footprint as round 3)
    float* gs      = (float*)(ws + 0);
    float* wa1     = (float*)(ws + 2048);
    float* wa2     = (float*)(ws + 5120);
    float* f1      = (float*)(ws + 8192);
    float* f2      = (float*)(ws + 139264);
    float* pmaxf1  = (float*)(ws + 270336);    // 1 MB (8 partials x 32K)
    float* psum    = (float*)(ws + 270336);    // aliases pmaxf1 (dead after k_cmax)
    float* colmax  = (float*)(ws + 1318912);
    float* rcolsum = (float*)(ws + 1449984);
    float* bnsum   = (float*)(ws + 1581056);
    float* bnsumsq = (float*)(ws + 1581312);
    u64*   maskp   = (u64*)  (ws + 1581568);   // 4 MB
    float* h       = (float*)(ws + 5775872);   // 8 MB
    float* outl    = (float*)(ws + 14164480);  // 8 MB
    float* outpre  = outl;                     // alias l=0 slice (safe, see k_reduce)

    float* out_main = (float*)d_out;
    float* out_gs   = out_main + 524288;

    hipMemsetAsync(bnsum, 0, 512, stream);   // bnsum + bnsumsq
    hipLaunchKernelGGL(k_gs,       dim3(1),    dim3(512), 0, stream,
                       gstate, Wg, W, a1, a2, gamma_g, beta_g, gs, wa1, wa2, out_gs);
    hipLaunchKernelGGL(k_h,        dim3(256),  dim3(256), 0, stream,
                       V, gsize, gs, W, wa1, wa2, h, f1, f2);
    hipLaunchKernelGGL(k_mask_max, dim3(1024), dim3(256), 0, stream,
                       A, f1, maskp, pmaxf1);
    hipLaunchKernelGGL(k_cmax,     dim3(128),  dim3(256), 0, stream,
                       pmaxf1, f2, colmax);
    hipLaunchKernelGGL(k_colsum,   dim3(512),  dim3(256), 0, stream,
                       maskp, f1, f2, colmax, psum);
    hipLaunchKernelGGL(k_csum,     dim3(128),  dim3(256), 0, stream,
                       psum, rcolsum);
    hipLaunchKernelGGL(k_pass2,    dim3(512),  dim3(256), 0, stream,
                       h, maskp, f1, f2, colmax, rcolsum, outl);
    hipLaunchKernelGGL(k_reduce,   dim3(128),  dim3(256), 0, stream,
                       outl, bias, outpre, bnsum, bnsumsq);
    hipLaunchKernelGGL(k_bnapply,  dim3(128),  dim3(256), 0, stream,
                       outpre, bnsum, bnsumsq, gamma_n, beta_n, out_main);
}

// Round 5
// 157.143 us; speedup vs baseline: 1.6270x; 1.4597x over previous
//
#include <hip/hip_runtime.h>
#include <hip/hip_fp16.h>

typedef unsigned long long u64;
typedef unsigned short ushort_t;
typedef __attribute__((ext_vector_type(8))) short short8v;   // 8 bf16 (4 VGPR)
typedef __attribute__((ext_vector_type(16))) float f32x16;   // MFMA accumulator

#define DI __device__ __forceinline__

DI unsigned cvt_pk_bf16(float lo, float hi) {   // u32 = {bf16(hi)<<16 | bf16(lo)}, RNE
    unsigned r;
    asm volatile("v_cvt_pk_bf16_f32 %0, %1, %2" : "=v"(r) : "v"(lo), "v"(hi));
    return r;
}

// Dims: b=8, N=1024, L=4, C=128, O=64, F=64, C+O=192
// ---------------------------------------------------------------------------
// k_gs: gs = global_state@Wg; gs BN+relu -> out_gs; wa1/wa2[l][c] = W[l][c][:].a{1,2}[l]
__global__ __launch_bounds__(512)
void k_gs(const float* gstate, const float* Wg, const float* W, const float* a1, const float* a2,
          const float* gamma_g, const float* beta_g, float* gs, float* wa1, float* wa2, float* outg)
{
    int t = threadIdx.x;
    int b = t >> 6, o = t & 63;
    float acc = 0.f;
    for (int c = 0; c < 128; ++c)
        acc += gstate[b*128 + c] * Wg[c*64 + o];
    __shared__ float sgs[512];
    __shared__ float mu_s[64], rs_s[64];
    sgs[t] = acc; gs[t] = acc;
    __syncthreads();
    if (t < 64) {
        float s = 0.f, sq = 0.f;
        for (int bb = 0; bb < 8; ++bb) { float v = sgs[bb*64 + t]; s += v; sq += v*v; }
        float mu = s * 0.125f;
        float var = sq * 0.125f - mu*mu;
        mu_s[t] = mu; rs_s[t] = rsqrtf(var + 1e-5f);
    }
    __syncthreads();
    {
        float v = (sgs[t] - mu_s[o]) * rs_s[o] * gamma_g[o] + beta_g[o];
        outg[t] = fmaxf(v, 0.f);
    }
    for (int e = t; e < 768; e += 512) {
        int l = e / 192, c = e - l*192;
        float s1 = 0.f, s2 = 0.f;
        const float* wp = W + (l*192 + c) * 64;
        for (int f = 0; f < 64; ++f) {
            float w = wp[f];
            s1 += w * a1[l*64 + f];
            s2 += w * a2[l*64 + f];
        }
        wa1[e] = s1; wa2[e] = s2;
    }
}

// ---------------------------------------------------------------------------
// k_h: hT[l][b][f][m] (bf16, m=node index) = (Vg @ W[l])^T; f1/f2[l][b][n] = Vg.wa{1,2}[l]
// grid 256 = (b=8) x (nt=32 tiles of 32 rows); block 256
__global__ __launch_bounds__(256)
void k_h(const float* V, const int* gsize, const float* gs, const float* W,
         const float* wa1, const float* wa2, ushort_t* hT, float* f1, float* f2)
{
    int blk = blockIdx.x;
    int b = blk >> 5, nt = blk & 31, n0 = nt * 32;
    int t = threadIdx.x;
    __shared__ float vg[32][194];
    {
        int r = t >> 3, c0 = (t & 7) * 16;
        const float* vp = V + ((size_t)(b*1024 + n0 + r) * 128 + c0);
        float4 v0 = *(const float4*)(vp + 0);
        float4 v1 = *(const float4*)(vp + 4);
        float4 v2 = *(const float4*)(vp + 8);
        float4 v3 = *(const float4*)(vp + 12);
        *(float4*)&vg[r][c0 + 0]  = v0;
        *(float4*)&vg[r][c0 + 4]  = v1;
        *(float4*)&vg[r][c0 + 8]  = v2;
        *(float4*)&vg[r][c0 + 12] = v3;
    }
    {
        int r = t >> 3, o0 = (t & 7) * 8;
        bool on = (n0 + r) < gsize[b];
        for (int j = 0; j < 8; ++j) vg[r][128 + o0 + j] = on ? gs[b*64 + o0 + j] : 0.f;
    }
    __syncthreads();
    int ty = t >> 5, tx = t & 31;
    int r0 = ty * 4;
    int j0 = tx * 8;
    int lw = j0 >> 6, f0 = j0 & 63;
    float acc[4][8];
    for (int i = 0; i < 4; ++i) for (int j = 0; j < 8; ++j) acc[i][j] = 0.f;
    const float* wp = W + (size_t)(lw*192) * 64 + f0;
    for (int c = 0; c < 192; ++c) {
        float4 wl = *(const float4*)(wp + c*64);
        float4 wh = *(const float4*)(wp + c*64 + 4);
        float wf[8] = {wl.x, wl.y, wl.z, wl.w, wh.x, wh.y, wh.z, wh.w};
        float a0 = vg[r0+0][c], a1v = vg[r0+1][c], a2v = vg[r0+2][c], a3v = vg[r0+3][c];
        for (int j = 0; j < 8; ++j) {
            acc[0][j] += a0  * wf[j];
            acc[1][j] += a1v * wf[j];
            acc[2][j] += a2v * wf[j];
            acc[3][j] += a3v * wf[j];
        }
    }
    int lb = lw*8 + b;
    #pragma unroll
    for (int j = 0; j < 8; ++j) {
        uint2 st;
        st.x = cvt_pk_bf16(acc[0][j], acc[1][j]);
        st.y = cvt_pk_bf16(acc[2][j], acc[3][j]);
        *(uint2*)(hT + ((size_t)(lb*64 + f0 + j)) * 1024 + n0 + r0) = st;
    }
    {
        int r = t & 31, l = (t >> 5) & 3, which = t >> 7;
        const float* wl = (which ? wa2 : wa1) + l*192;
        float s = 0.f;
        for (int c = 0; c < 192; ++c) s += vg[r][c] * wl[c];
        float* dst = which ? f2 : f1;
        dst[(l*8 + b) * 1024 + n0 + r] = s;
    }
}

// ---------------------------------------------------------------------------
// k_mask_max: stream A -> ballot-packed mask + per-column partial max of masked f1.
// ILP-16: 16 rows' loads in flight before ballots (latency fix, was VGPR=8/unroll-4).
// grid 1024 = b(8) x l(4) x nc(8: 128-row chunks) x wg(4); block 256
__global__ __launch_bounds__(256)
void k_mask_max(const float* A, const float* f1, u64* maskp, float* pmaxf1)
{
    int blk = blockIdx.x;
    int wg = blk & 3, nc = (blk >> 2) & 7, l = (blk >> 5) & 3, b = blk >> 7;
    int t = threadIdx.x;
    int wv = t >> 6, lane = t & 63;
    int w = wg*4 + wv;
    int m = w*64 + lane;
    int n0 = nc*128;
    int lb = l*8 + b;
    __shared__ float f1s[128];
    if (t < 128) f1s[t] = f1[lb*1024 + n0 + t];
    __syncthreads();
    float mx = -3.0e38f;
    const float* Ap = A + (((size_t)(b*1024 + n0) * 4 + l) * 1024 + m);
    u64* mp = maskp + ((size_t)(b*1024 + n0) * 4 + l) * 16 + w;
    for (int nb = 0; nb < 8; ++nb) {
        float av[16];
        #pragma unroll
        for (int k = 0; k < 16; ++k) av[k] = Ap[(size_t)(nb*16 + k) * 4096];
        #pragma unroll
        for (int k = 0; k < 16; ++k) {
            bool pos = av[k] > 0.f;
            u64 bal = __ballot(pos);
            if (lane == 0) mp[(size_t)(nb*16 + k) * 64] = bal;
            if (pos) mx = fmaxf(mx, f1s[nb*16 + k]);
        }
    }
    pmaxf1[nc*32768 + lb*1024 + m] = mx;
}

// ---------------------------------------------------------------------------
// k_cmax: colmax[lbm] = empty ? -9e15 : leaky(f2 + max over 8 partials)
__global__ __launch_bounds__(256)
void k_cmax(const float* pmaxf1, const float* f2, float* colmax)
{
    int i = blockIdx.x * 256 + threadIdx.x;   // 32768
    float mx = pmaxf1[i];
    for (int k = 1; k < 8; ++k) mx = fmaxf(mx, pmaxf1[k*32768 + i]);
    float e = f2[i] + mx;
    e = e > 0.f ? e : 0.2f * e;
    colmax[i] = (mx < -1e38f) ? -9e15f : e;
}

// ---------------------------------------------------------------------------
// k_colsum: psum[nc][lbm] = sum_n exp((mask? e : NEG) - colmax)
// grid 512 = l(4) x b(8) x mc(4) x nc(4); block 256 (1 col/thread)
__global__ __launch_bounds__(256)
void k_colsum(const u64* maskp, const float* f1, const float* f2, const float* colmax, float* psum)
{
    int blk = blockIdx.x;
    int nc = blk & 3, mc = (blk >> 2) & 3, b = (blk >> 4) & 7, l = blk >> 7;
    int t = threadIdx.x;
    int lb = l*8 + b;
    int m = mc*256 + t;
    int n0 = nc*256;
    __shared__ float f1s[256];
    __shared__ u64 wlds[1024];
    f1s[t] = f1[lb*1024 + n0 + t];
    for (int k = 0; k < 4; ++k) {
        int e = t + k*256;
        int n = e >> 2, ws_ = e & 3;
        wlds[e] = maskp[((size_t)(b*1024 + n0 + n) * 4 + l) * 16 + mc*4 + ws_];
    }
    __syncthreads();
    float f2v = f2[lb*1024 + m];
    float cm  = colmax[lb*1024 + m];
    int wv = t >> 6;
    int bit = t & 63;
    float s = 0.f;
    #pragma unroll 4
    for (int n = 0; n < 256; ++n) {
        u64 word = wlds[n*4 + wv];
        float e1 = f1s[n] + f2v;
        e1 = e1 > 0.f ? e1 : 0.2f * e1;
        float v = ((word >> bit) & 1) ? e1 : -9e15f;
        s += __expf(v - cm);
    }
    psum[nc*32768 + lb*1024 + m] = s;
}

// ---------------------------------------------------------------------------
// k_csum: ecol = empty?0:exp(-colmax)/s; base = empty? 1/s : 0
__global__ __launch_bounds__(256)
void k_csum(const float* psum, const float* colmax, float* ecol, float* base)
{
    int i = blockIdx.x * 256 + threadIdx.x;
    float s = psum[i] + psum[32768 + i] + psum[65536 + i] + psum[98304 + i];
    float rs = 1.f / s;
    float cm = colmax[i];
    bool emp = (cm == -9e15f);
    ecol[i] = emp ? 0.f : __expf(-cm) * rs;
    base[i] = emp ? rs : 0.f;
}

// ---------------------------------------------------------------------------
// k_pass2: MFMA. outl2[sl=ks*4+l][b][n][f] (f16) = sum_{m in K-half} att[n,m]*h[m,f]
// att generated in registers in A-frag layout: row=lane&31, k=8*(lane>>5)+i.
// grid 512 = ks(2) x l(4) x b(8) x nt(8 tiles of 128 n-rows); block 256 (4 waves: 32n x 64f each)
__global__ __launch_bounds__(256)
void k_pass2(const ushort_t* hT, const u64* maskp, const float* f1,
             const float* f2, const float* ecol, const float* base, __half* outl2)
{
    int blk = blockIdx.x;
    int nt = blk & 7, b = (blk >> 3) & 7, l = (blk >> 6) & 3, ks = blk >> 8;
    int lb = l*8 + b;
    int n0 = nt*128;
    int m0 = ks*512;
    int t = threadIdx.x;
    int w = t >> 6, lane = t & 63;
    int rl = lane & 31, kg = lane >> 5;

    __shared__ float f2t[512], ect[512], bat[512];
    __shared__ ushort_t hl[64][72];   // 64 f x 64 m bf16 chunk, pad 72 (4-way conflicts max)

    for (int k = 0; k < 2; ++k) {
        int j = t + k*256;
        f2t[j] = f2[lb*1024 + m0 + j];
        ect[j] = ecol[lb*1024 + m0 + j];
        bat[j] = base[lb*1024 + m0 + j];
    }
    int nrow = n0 + w*32 + rl;
    float f1v = f1[lb*1024 + nrow];
    const u64* mrow = maskp + ((size_t)(b*1024 + nrow)*4 + l)*16 + ks*8;

    f32x16 acc0 = {0,0,0,0,0,0,0,0,0,0,0,0,0,0,0,0};
    f32x16 acc1 = {0,0,0,0,0,0,0,0,0,0,0,0,0,0,0,0};

    int hf = t >> 2, hseg = t & 3;
    const ushort_t* hsrc = hT + ((size_t)(lb*64 + hf)) * 1024 + m0 + hseg*16;

    for (int kc = 0; kc < 8; ++kc) {
        __syncthreads();
        {   // stage 64f x 64m bf16 chunk
            const uint4* s = (const uint4*)(hsrc + kc*64);
            uint4 q0 = s[0], q1 = s[1];
            *(uint4*)&hl[hf][hseg*16]     = q0;
            *(uint4*)&hl[hf][hseg*16 + 8] = q1;
        }
        u64 wm = mrow[kc];
        __syncthreads();
        #pragma unroll
        for (int kk = 0; kk < 4; ++kk) {
            int jb = kc*64 + kk*16 + kg*8;
            float4 fa = *(float4*)&f2t[jb];
            float4 fb = *(float4*)&f2t[jb+4];
            float4 ea = *(float4*)&ect[jb];
            float4 eb = *(float4*)&ect[jb+4];
            float4 ba = *(float4*)&bat[jb];
            float4 bb = *(float4*)&bat[jb+4];
            unsigned mb = (unsigned)(wm >> (kk*16 + kg*8)) & 0xffu;
            float xs[8] = {fa.x,fa.y,fa.z,fa.w,fb.x,fb.y,fb.z,fb.w};
            float es[8] = {ea.x,ea.y,ea.z,ea.w,eb.x,eb.y,eb.z,eb.w};
            float bs[8] = {ba.x,ba.y,ba.z,ba.w,bb.x,bb.y,bb.z,bb.w};
            float av[8];
            #pragma unroll
            for (int i = 0; i < 8; ++i) {
                float x = f1v + xs[i];
                x = fmaxf(x, 0.2f * x);          // leaky_relu(0.2)
                float p = __expf(x) * es[i];
                av[i] = (mb & (1u << i)) ? p : bs[i];
            }
            union { unsigned u[4]; short8v s; } af;
            af.u[0] = cvt_pk_bf16(av[0], av[1]);
            af.u[1] = cvt_pk_bf16(av[2], av[3]);
            af.u[2] = cvt_pk_bf16(av[4], av[5]);
            af.u[3] = cvt_pk_bf16(av[6], av[7]);
            short8v b0 = *(short8v*)&hl[rl][kk*16 + kg*8];
            short8v b1 = *(short8v*)&hl[32 + rl][kk*16 + kg*8];
            acc0 = __builtin_amdgcn_mfma_f32_32x32x16_bf16(af.s, b0, acc0, 0, 0, 0);
            acc1 = __builtin_amdgcn_mfma_f32_32x32x16_bf16(af.s, b1, acc1, 0, 0, 0);
        }
    }
    int sl = ks*4 + l;
    __half* op = outl2 + ((size_t)(sl*8 + b) * 1024) * 64;
    #pragma unroll
    for (int r = 0; r < 16; ++r) {
        int row = n0 + w*32 + (r & 3) + 8*(r >> 2) + 4*kg;   // C/D layout (m74/m101)
        op[(size_t)row*64 + rl]      = __float2half(acc0[r]);
        op[(size_t)row*64 + 32 + rl] = __float2half(acc1[r]);
    }
}

// ---------------------------------------------------------------------------
// k_reduce: outpre = sum_{8 slices} outl2 + bias; BN partial sums (LDS + global atomics)
// grid 256 x 256 thr x 8 elems = 524288
__global__ __launch_bounds__(256)
void k_reduce(const __half* outl2, const float* bias, float* outpre, float* bnsum, float* bnsumsq)
{
    int blk = blockIdx.x, t = threadIdx.x;
    __shared__ float red[2][64];
    if (t < 128) red[t >> 6][t & 63] = 0.f;
    __syncthreads();
    size_t idx = (size_t)blk * 2048 + t * 8;
    int fb = (t * 8) & 63;
    float o[8];
    for (int j = 0; j < 8; ++j) o[j] = bias[fb + j];
    #pragma unroll
    for (int sl = 0; sl < 8; ++sl) {
        uint4 u = *(const uint4*)(outl2 + (size_t)sl * 524288 + idx);
        const __half* hh = (const __half*)&u;
        #pragma unroll
        for (int j = 0; j < 8; ++j) o[j] += __half2float(hh[j]);
    }
    *(float4*)(outpre + idx)     = make_float4(o[0], o[1], o[2], o[3]);
    *(float4*)(outpre + idx + 4) = make_float4(o[4], o[5], o[6], o[7]);
    for (int j = 0; j < 8; ++j) {
        atomicAdd(&red[0][fb + j], o[j]);
        atomicAdd(&red[1][fb + j], o[j]*o[j]);
    }
    __syncthreads();
    if (t < 64) { atomicAdd(&bnsum[t], red[0][t]); atomicAdd(&bnsumsq[t], red[1][t]); }
}

// ---------------------------------------------------------------------------
// grid 128 (covers exactly 524288 output elems)
__global__ __launch_bounds__(256)
void k_bnapply(const float* outpre, const float* bnsum, const float* bnsumsq,
               const float* gamma, const float* beta, float* out)
{
    int blk = blockIdx.x, t = threadIdx.x;
    int f0 = (t * 4) & 63;
    float mu[4], rstd[4], ga[4], be[4];
    for (int j = 0; j < 4; ++j) {
        float sm = bnsum[f0 + j], sq = bnsumsq[f0 + j];
        float m = sm * (1.f / 8192.f);
        float var = sq * (1.f / 8192.f) - m*m;
        mu[j] = m; rstd[j] = rsqrtf(var + 1e-5f);
        ga[j] = gamma[f0 + j]; be[j] = beta[f0 + j];
    }
    for (int g = 0; g < 4; ++g) {
        size_t base = (size_t)blk * 4096 + g * 1024 + t * 4;
        float4 v = *(const float4*)(outpre + base);
        float x[4] = {v.x, v.y, v.z, v.w};
        float y[4];
        for (int j = 0; j < 4; ++j) {
            float z = (x[j] - mu[j]) * rstd[j] * ga[j] + be[j];
            y[j] = fmaxf(z, 0.f);
        }
        *(float4*)(out + base) = make_float4(y[0], y[1], y[2], y[3]);
    }
}

// ---------------------------------------------------------------------------
extern "C" void kernel_launch(void* const* d_in, const int* in_sizes, int n_in,
                              void* d_out, int out_size, void* d_ws, size_t ws_size,
                              hipStream_t stream)
{
    const float* V       = (const float*)d_in[0];
    const float* A       = (const float*)d_in[1];
    const float* gstate  = (const float*)d_in[2];
    const int*   gsize   = (const int*)d_in[3];
    // d_in[4] subgraph_size: unused by reference
    const float* Wg      = (const float*)d_in[5];
    const float* W       = (const float*)d_in[6];
    const float* a1      = (const float*)d_in[7];
    const float* a2      = (const float*)d_in[8];
    const float* bias    = (const float*)d_in[9];
    const float* gamma_n = (const float*)d_in[10];
    const float* beta_n  = (const float*)d_in[11];
    const float* gamma_g = (const float*)d_in[12];
    const float* beta_g  = (const float*)d_in[13];

    char* ws = (char*)d_ws;               // ~19.6 MB used
    float*    gs      = (float*)(ws + 0);
    float*    wa1     = (float*)(ws + 2048);
    float*    wa2     = (float*)(ws + 5120);
    float*    f1      = (float*)(ws + 8192);
    float*    f2      = (float*)(ws + 139264);
    float*    pmaxf1  = (float*)(ws + 270336);    // 1 MB; psum aliases (sequential use)
    float*    psum    = (float*)(ws + 270336);
    float*    colmax  = (float*)(ws + 1318912);
    float*    ecol    = (float*)(ws + 1449984);
    float*    base    = (float*)(ws + 1581056);
    float*    bnsum   = (float*)(ws + 1712128);
    float*    bnsumsq = (float*)(ws + 1712384);
    u64*      maskp   = (u64*)  (ws + 1712640);   // 4 MB
    ushort_t* hT      = (ushort_t*)(ws + 5906944);   // 4 MB bf16
    __half*   outl2   = (__half*)(ws + 10101248);    // 8 MB (8 slices f16)
    float*    outpre  = (float*)(ws + 18489856);     // 2 MB

    float* out_main = (float*)d_out;
    float* out_gs   = out_main + 524288;

    hipMemsetAsync(bnsum, 0, 512, stream);   // bnsum + bnsumsq
    hipLaunchKernelGGL(k_gs,       dim3(1),    dim3(512), 0, stream,
                       gstate, Wg, W, a1, a2, gamma_g, beta_g, gs, wa1, wa2, out_gs);
    hipLaunchKernelGGL(k_h,        dim3(256),  dim3(256), 0, stream,
                       V, gsize, gs, W, wa1, wa2, hT, f1, f2);
    hipLaunchKernelGGL(k_mask_max, dim3(1024), dim3(256), 0, stream,
                       A, f1, maskp, pmaxf1);
    hipLaunchKernelGGL(k_cmax,     dim3(128),  dim3(256), 0, stream,
                       pmaxf1, f2, colmax);
    hipLaunchKernelGGL(k_colsum,   dim3(512),  dim3(256), 0, stream,
                       maskp, f1, f2, colmax, psum);
    hipLaunchKernelGGL(k_csum,     dim3(128),  dim3(256), 0, stream,
                       psum, colmax, ecol, base);
    hipLaunchKernelGGL(k_pass2,    dim3(512),  dim3(256), 0, stream,
                       hT, maskp, f1, f2, ecol, base, outl2);
    hipLaunchKernelGGL(k_reduce,   dim3(256),  dim3(256), 0, stream,
                       outl2, bias, outpre, bnsum, bnsumsq);
    hipLaunchKernelGGL(k_bnapply,  dim3(128),  dim3(256), 0, stream,
                       outpre, bnsum, bnsumsq, gamma_n, beta_n, out_main);
}

// Round 7
// 144.543 us; speedup vs baseline: 1.7688x; 1.0872x over previous
//
#include <hip/hip_runtime.h>
#include <hip/hip_fp16.h>

typedef unsigned long long u64;
typedef unsigned short ushort_t;
typedef __attribute__((ext_vector_type(8))) short short8v;   // 8 bf16 (4 VGPR)
typedef __attribute__((ext_vector_type(16))) float f32x16;   // MFMA accumulator

#define DI __device__ __forceinline__

DI unsigned cvt_pk_bf16(float lo, float hi) {   // u32 = {bf16(hi)<<16 | bf16(lo)}, RNE
    unsigned r;
    asm volatile("v_cvt_pk_bf16_f32 %0, %1, %2" : "=v"(r) : "v"(lo), "v"(hi));
    return r;
}

// Dims: b=8, N=1024, L=4, C=128, O=64, F=64, C+O=192
// ---------------------------------------------------------------------------
// k_gs: gs = global_state@Wg; gs BN+relu -> out_gs; wa1/wa2[l][c] = W[l][c][:].a{1,2}[l]
__global__ __launch_bounds__(512)
void k_gs(const float* gstate, const float* Wg, const float* W, const float* a1, const float* a2,
          const float* gamma_g, const float* beta_g, float* gs, float* wa1, float* wa2, float* outg)
{
    int t = threadIdx.x;
    int b = t >> 6, o = t & 63;
    float acc = 0.f;
    for (int c = 0; c < 128; ++c)
        acc += gstate[b*128 + c] * Wg[c*64 + o];
    __shared__ float sgs[512];
    __shared__ float mu_s[64], rs_s[64];
    sgs[t] = acc; gs[t] = acc;
    __syncthreads();
    if (t < 64) {
        float s = 0.f, sq = 0.f;
        for (int bb = 0; bb < 8; ++bb) { float v = sgs[bb*64 + t]; s += v; sq += v*v; }
        float mu = s * 0.125f;
        float var = sq * 0.125f - mu*mu;
        mu_s[t] = mu; rs_s[t] = rsqrtf(var + 1e-5f);
    }
    __syncthreads();
    {
        float v = (sgs[t] - mu_s[o]) * rs_s[o] * gamma_g[o] + beta_g[o];
        outg[t] = fmaxf(v, 0.f);
    }
    for (int e = t; e < 768; e += 512) {
        int l = e / 192, c = e - l*192;
        float s1 = 0.f, s2 = 0.f;
        const float* wp = W + (l*192 + c) * 64;
        for (int f = 0; f < 64; ++f) {
            float w = wp[f];
            s1 += w * a1[l*64 + f];
            s2 += w * a2[l*64 + f];
        }
        wa1[e] = s1; wa2[e] = s2;
    }
}

// ---------------------------------------------------------------------------
// k_h: hT[l][b][f][m] (bf16, m=node index) = (Vg @ W[l])^T; f1/f2[l][b][n] = Vg.wa{1,2}[l]
// grid 256 = (b=8) x (nt=32 tiles of 32 rows); block 256
__global__ __launch_bounds__(256)
void k_h(const float* V, const int* gsize, const float* gs, const float* W,
         const float* wa1, const float* wa2, ushort_t* hT, float* f1, float* f2)
{
    int blk = blockIdx.x;
    int b = blk >> 5, nt = blk & 31, n0 = nt * 32;
    int t = threadIdx.x;
    __shared__ float vg[32][194];
    {
        int r = t >> 3, c0 = (t & 7) * 16;
        const float* vp = V + ((size_t)(b*1024 + n0 + r) * 128 + c0);
        float4 v0 = *(const float4*)(vp + 0);
        float4 v1 = *(const float4*)(vp + 4);
        float4 v2 = *(const float4*)(vp + 8);
        float4 v3 = *(const float4*)(vp + 12);
        *(float4*)&vg[r][c0 + 0]  = v0;
        *(float4*)&vg[r][c0 + 4]  = v1;
        *(float4*)&vg[r][c0 + 8]  = v2;
        *(float4*)&vg[r][c0 + 12] = v3;
    }
    {
        int r = t >> 3, o0 = (t & 7) * 8;
        bool on = (n0 + r) < gsize[b];
        for (int j = 0; j < 8; ++j) vg[r][128 + o0 + j] = on ? gs[b*64 + o0 + j] : 0.f;
    }
    __syncthreads();
    int ty = t >> 5, tx = t & 31;
    int r0 = ty * 4;
    int j0 = tx * 8;
    int lw = j0 >> 6, f0 = j0 & 63;
    float acc[4][8];
    for (int i = 0; i < 4; ++i) for (int j = 0; j < 8; ++j) acc[i][j] = 0.f;
    const float* wp = W + (size_t)(lw*192) * 64 + f0;
    for (int c = 0; c < 192; ++c) {
        float4 wl = *(const float4*)(wp + c*64);
        float4 wh = *(const float4*)(wp + c*64 + 4);
        float wf[8] = {wl.x, wl.y, wl.z, wl.w, wh.x, wh.y, wh.z, wh.w};
        float a0 = vg[r0+0][c], a1v = vg[r0+1][c], a2v = vg[r0+2][c], a3v = vg[r0+3][c];
        for (int j = 0; j < 8; ++j) {
            acc[0][j] += a0  * wf[j];
            acc[1][j] += a1v * wf[j];
            acc[2][j] += a2v * wf[j];
            acc[3][j] += a3v * wf[j];
        }
    }
    int lb = lw*8 + b;
    #pragma unroll
    for (int j = 0; j < 8; ++j) {
        uint2 st;
        st.x = cvt_pk_bf16(acc[0][j], acc[1][j]);
        st.y = cvt_pk_bf16(acc[2][j], acc[3][j]);
        *(uint2*)(hT + ((size_t)(lb*64 + f0 + j)) * 1024 + n0 + r0) = st;
    }
    {
        int r = t & 31, l = (t >> 5) & 3, which = t >> 7;
        const float* wl = (which ? wa2 : wa1) + l*192;
        float s = 0.f;
        for (int c = 0; c < 192; ++c) s += vg[r][c] * wl[c];
        float* dst = which ? f2 : f1;
        dst[(l*8 + b) * 1024 + n0 + r] = s;
    }
}

// ---------------------------------------------------------------------------
// k_mask_max v3: WAVE-PER-ROW. One wave reads a full (b,n,l) row (4 KB contiguous)
// as 16 stride-64 loads; ballot k -> mask word k directly; column-max is lane-local
// mx[k] (column m=64k+lane). Word k parked in lane k via cndmask -> one 128B store.
// grid 1024 = b(8) x l(4) x nc(32: 32-row chunks); block 256 (4 waves x 8 rows)
__global__ __launch_bounds__(256)
void k_mask_max(const float* A, const float* f1, u64* maskp, float* pmaxf1)
{
    int blk = blockIdx.x;
    int nc = blk & 31, l = (blk >> 5) & 3, b = blk >> 7;
    int t = threadIdx.x;
    int wv = t >> 6, lane = t & 63;
    int lb = l*8 + b;
    int n0 = nc*32 + wv*8;
    const float* f1p = f1 + lb*1024;
    float mx[16];
    #pragma unroll
    for (int k = 0; k < 16; ++k) mx[k] = -3.0e38f;

    for (int r = 0; r < 8; ++r) {
        int n = n0 + r;
        const float* Ap = A + (((size_t)(b*1024 + n) * 4 + l) * 1024) + lane;
        float av[16];
        #pragma unroll
        for (int k = 0; k < 16; ++k) av[k] = Ap[k*64];
        float f1n = f1p[n];
        unsigned vlo = 0, vhi = 0;
        #pragma unroll
        for (int k = 0; k < 16; ++k) {
            bool pos = av[k] > 0.f;
            u64 bal = __ballot(pos);
            if (lane == k) { vlo = (unsigned)(bal & 0xffffffffu); vhi = (unsigned)(bal >> 32); }
            if (pos) mx[k] = fmaxf(mx[k], f1n);
        }
        if (lane < 16) {
            uint2 st; st.x = vlo; st.y = vhi;
            *(uint2*)(maskp + ((size_t)(b*1024 + n)*4 + l)*16 + lane) = st;
        }
    }
    // block-reduce the 4 waves' column maxima -> pmaxf1[nc][lb*1024 + m]
    __shared__ float mxs[4][16][64];   // 16 KB
    #pragma unroll
    for (int k = 0; k < 16; ++k) mxs[wv][k][lane] = mx[k];
    __syncthreads();
    for (int q = 0; q < 4; ++q) {
        int idx = t + q*256;           // idx = k*64 + lane2
        int k = idx >> 6, lane2 = idx & 63;
        float m0 = fmaxf(fmaxf(mxs[0][k][lane2], mxs[1][k][lane2]),
                         fmaxf(mxs[2][k][lane2], mxs[3][k][lane2]));
        pmaxf1[(size_t)nc*32768 + lb*1024 + idx] = m0;
    }
}

// ---------------------------------------------------------------------------
// k_cmax: colmax[lbm] = empty ? -9e15 : leaky(f2 + max over 32 partials)
__global__ __launch_bounds__(256)
void k_cmax(const float* pmaxf1, const float* f2, float* colmax)
{
    int i = blockIdx.x * 256 + threadIdx.x;   // 32768
    float mx = pmaxf1[i];
    #pragma unroll
    for (int k = 1; k < 32; ++k) mx = fmaxf(mx, pmaxf1[k*32768 + i]);
    float e = f2[i] + mx;
    e = e > 0.f ? e : 0.2f * e;
    colmax[i] = (mx < -1e38f) ? -9e15f : e;
}

// ---------------------------------------------------------------------------
// k_colsum: psum[nc][lbm] = sum_n exp((mask? e : NEG) - colmax)
// grid 512 = l(4) x b(8) x mc(4) x nc(4); block 256 (1 col/thread)
__global__ __launch_bounds__(256)
void k_colsum(const u64* maskp, const float* f1, const float* f2, const float* colmax, float* psum)
{
    int blk = blockIdx.x;
    int nc = blk & 3, mc = (blk >> 2) & 3, b = (blk >> 4) & 7, l = blk >> 7;
    int t = threadIdx.x;
    int lb = l*8 + b;
    int m = mc*256 + t;
    int n0 = nc*256;
    __shared__ float f1s[256];
    __shared__ u64 wlds[1024];
    f1s[t] = f1[lb*1024 + n0 + t];
    for (int k = 0; k < 4; ++k) {
        int e = t + k*256;
        int n = e >> 2, ws_ = e & 3;
        wlds[e] = maskp[((size_t)(b*1024 + n0 + n) * 4 + l) * 16 + mc*4 + ws_];
    }
    __syncthreads();
    float f2v = f2[lb*1024 + m];
    float cm  = colmax[lb*1024 + m];
    int wv = t >> 6;
    int bit = t & 63;
    float s = 0.f;
    #pragma unroll 4
    for (int n = 0; n < 256; ++n) {
        u64 word = wlds[n*4 + wv];
        float e1 = f1s[n] + f2v;
        e1 = e1 > 0.f ? e1 : 0.2f * e1;
        float v = ((word >> bit) & 1) ? e1 : -9e15f;
        s += __expf(v - cm);
    }
    psum[nc*32768 + lb*1024 + m] = s;
}

// ---------------------------------------------------------------------------
// k_csum: ecol = empty?0:exp(-colmax)/s; base = empty? 1/s : 0
__global__ __launch_bounds__(256)
void k_csum(const float* psum, const float* colmax, float* ecol, float* base)
{
    int i = blockIdx.x * 256 + threadIdx.x;
    float s = psum[i] + psum[32768 + i] + psum[65536 + i] + psum[98304 + i];
    float rs = 1.f / s;
    float cm = colmax[i];
    bool emp = (cm == -9e15f);
    ecol[i] = emp ? 0.f : __expf(-cm) * rs;
    base[i] = emp ? rs : 0.f;
}

// ---------------------------------------------------------------------------
// k_pass2: MFMA. outl2[sl=ks*4+l][b][n][f] (f16) = sum_{m in K-half} att[n,m]*h[m,f]
// att generated in registers in A-frag layout: row=lane&31, k=8*(lane>>5)+i.
// grid 512 = ks(2) x l(4) x b(8) x nt(8 tiles of 128 n-rows); block 256 (4 waves: 32n x 64f each)
__global__ __launch_bounds__(256)
void k_pass2(const ushort_t* hT, const u64* maskp, const float* f1,
             const float* f2, const float* ecol, const float* base, __half* outl2)
{
    int blk = blockIdx.x;
    int nt = blk & 7, b = (blk >> 3) & 7, l = (blk >> 6) & 3, ks = blk >> 8;
    int lb = l*8 + b;
    int n0 = nt*128;
    int m0 = ks*512;
    int t = threadIdx.x;
    int w = t >> 6, lane = t & 63;
    int rl = lane & 31, kg = lane >> 5;

    __shared__ float f2t[512], ect[512], bat[512];
    __shared__ ushort_t hl[64][72];   // 64 f x 64 m bf16 chunk, pad 72

    for (int k = 0; k < 2; ++k) {
        int j = t + k*256;
        f2t[j] = f2[lb*1024 + m0 + j];
        ect[j] = ecol[lb*1024 + m0 + j];
        bat[j] = base[lb*1024 + m0 + j];
    }
    int nrow = n0 + w*32 + rl;
    float f1v = f1[lb*1024 + nrow];
    const u64* mrow = maskp + ((size_t)(b*1024 + nrow)*4 + l)*16 + ks*8;

    f32x16 acc0 = {0,0,0,0,0,0,0,0,0,0,0,0,0,0,0,0};
    f32x16 acc1 = {0,0,0,0,0,0,0,0,0,0,0,0,0,0,0,0};

    int hf = t >> 2, hseg = t & 3;
    const ushort_t* hsrc = hT + ((size_t)(lb*64 + hf)) * 1024 + m0 + hseg*16;

    for (int kc = 0; kc < 8; ++kc) {
        __syncthreads();
        {   // stage 64f x 64m bf16 chunk
            const uint4* s = (const uint4*)(hsrc + kc*64);
            uint4 q0 = s[0], q1 = s[1];
            *(uint4*)&hl[hf][hseg*16]     = q0;
            *(uint4*)&hl[hf][hseg*16 + 8] = q1;
        }
        u64 wm = mrow[kc];
        __syncthreads();
        #pragma unroll
        for (int kk = 0; kk < 4; ++kk) {
            int jb = kc*64 + kk*16 + kg*8;
            float4 fa = *(float4*)&f2t[jb];
            float4 fb = *(float4*)&f2t[jb+4];
            float4 ea = *(float4*)&ect[jb];
            float4 eb = *(float4*)&ect[jb+4];
            float4 ba = *(float4*)&bat[jb];
            float4 bb = *(float4*)&bat[jb+4];
            unsigned mb = (unsigned)(wm >> (kk*16 + kg*8)) & 0xffu;
            float xs[8] = {fa.x,fa.y,fa.z,fa.w,fb.x,fb.y,fb.z,fb.w};
            float es[8] = {ea.x,ea.y,ea.z,ea.w,eb.x,eb.y,eb.z,eb.w};
            float bs[8] = {ba.x,ba.y,ba.z,ba.w,bb.x,bb.y,bb.z,bb.w};
            float av[8];
            #pragma unroll
            for (int i = 0; i < 8; ++i) {
                float x = f1v + xs[i];
                x = fmaxf(x, 0.2f * x);          // leaky_relu(0.2)
                float p = __expf(x) * es[i];
                av[i] = (mb & (1u << i)) ? p : bs[i];
            }
            union { unsigned u[4]; short8v s; } af;
            af.u[0] = cvt_pk_bf16(av[0], av[1]);
            af.u[1] = cvt_pk_bf16(av[2], av[3]);
            af.u[2] = cvt_pk_bf16(av[4], av[5]);
            af.u[3] = cvt_pk_bf16(av[6], av[7]);
            short8v b0 = *(short8v*)&hl[rl][kk*16 + kg*8];
            short8v b1 = *(short8v*)&hl[32 + rl][kk*16 + kg*8];
            acc0 = __builtin_amdgcn_mfma_f32_32x32x16_bf16(af.s, b0, acc0, 0, 0, 0);
            acc1 = __builtin_amdgcn_mfma_f32_32x32x16_bf16(af.s, b1, acc1, 0, 0, 0);
        }
    }
    int sl = ks*4 + l;
    __half* op = outl2 + ((size_t)(sl*8 + b) * 1024) * 64;
    #pragma unroll
    for (int r = 0; r < 16; ++r) {
        int row = n0 + w*32 + (r & 3) + 8*(r >> 2) + 4*kg;   // C/D layout (m74/m101)
        op[(size_t)row*64 + rl]      = __float2half(acc0[r]);
        op[(size_t)row*64 + 32 + rl] = __float2half(acc1[r]);
    }
}

// ---------------------------------------------------------------------------
// k_reduce: outpre = sum_{8 slices} outl2 + bias; BN partial sums (LDS + global atomics)
// grid 256 x 256 thr x 8 elems = 524288
__global__ __launch_bounds__(256)
void k_reduce(const __half* outl2, const float* bias, float* outpre, float* bnsum, float* bnsumsq)
{
    int blk = blockIdx.x, t = threadIdx.x;
    __shared__ float red[2][64];
    if (t < 128) red[t >> 6][t & 63] = 0.f;
    __syncthreads();
    size_t idx = (size_t)blk * 2048 + t * 8;
    int fb = (t * 8) & 63;
    float o[8];
    for (int j = 0; j < 8; ++j) o[j] = bias[fb + j];
    #pragma unroll
    for (int sl = 0; sl < 8; ++sl) {
        uint4 u = *(const uint4*)(outl2 + (size_t)sl * 524288 + idx);
        const __half* hh = (const __half*)&u;
        #pragma unroll
        for (int j = 0; j < 8; ++j) o[j] += __half2float(hh[j]);
    }
    *(float4*)(outpre + idx)     = make_float4(o[0], o[1], o[2], o[3]);
    *(float4*)(outpre + idx + 4) = make_float4(o[4], o[5], o[6], o[7]);
    for (int j = 0; j < 8; ++j) {
        atomicAdd(&red[0][fb + j], o[j]);
        atomicAdd(&red[1][fb + j], o[j]*o[j]);
    }
    __syncthreads();
    if (t < 64) { atomicAdd(&bnsum[t], red[0][t]); atomicAdd(&bnsumsq[t], red[1][t]); }
}

// ---------------------------------------------------------------------------
// grid 128 (covers exactly 524288 output elems)
__global__ __launch_bounds__(256)
void k_bnapply(const float* outpre, const float* bnsum, const float* bnsumsq,
               const float* gamma, const float* beta, float* out)
{
    int blk = blockIdx.x, t = threadIdx.x;
    int f0 = (t * 4) & 63;
    float mu[4], rstd[4], ga[4], be[4];
    for (int j = 0; j < 4; ++j) {
        float sm = bnsum[f0 + j], sq = bnsumsq[f0 + j];
        float m = sm * (1.f / 8192.f);
        float var = sq * (1.f / 8192.f) - m*m;
        mu[j] = m; rstd[j] = rsqrtf(var + 1e-5f);
        ga[j] = gamma[f0 + j]; be[j] = beta[f0 + j];
    }
    for (int g = 0; g < 4; ++g) {
        size_t base = (size_t)blk * 4096 + g * 1024 + t * 4;
        float4 v = *(const float4*)(outpre + base);
        float x[4] = {v.x, v.y, v.z, v.w};
        float y[4];
        for (int j = 0; j < 4; ++j) {
            float z = (x[j] - mu[j]) * rstd[j] * ga[j] + be[j];
            y[j] = fmaxf(z, 0.f);
        }
        *(float4*)(out + base) = make_float4(y[0], y[1], y[2], y[3]);
    }
}

// ---------------------------------------------------------------------------
extern "C" void kernel_launch(void* const* d_in, const int* in_sizes, int n_in,
                              void* d_out, int out_size, void* d_ws, size_t ws_size,
                              hipStream_t stream)
{
    const float* V       = (const float*)d_in[0];
    const float* A       = (const float*)d_in[1];
    const float* gstate  = (const float*)d_in[2];
    const int*   gsize   = (const int*)d_in[3];
    // d_in[4] subgraph_size: unused by reference
    const float* Wg      = (const float*)d_in[5];
    const float* W       = (const float*)d_in[6];
    const float* a1      = (const float*)d_in[7];
    const float* a2      = (const float*)d_in[8];
    const float* bias    = (const float*)d_in[9];
    const float* gamma_n = (const float*)d_in[10];
    const float* beta_n  = (const float*)d_in[11];
    const float* gamma_g = (const float*)d_in[12];
    const float* beta_g  = (const float*)d_in[13];

    char* ws = (char*)d_ws;               // ~22.6 MB used
    float*    gs      = (float*)(ws + 0);
    float*    wa1     = (float*)(ws + 2048);
    float*    wa2     = (float*)(ws + 5120);
    float*    f1      = (float*)(ws + 8192);
    float*    f2      = (float*)(ws + 139264);
    float*    colmax  = (float*)(ws + 270336);
    float*    ecol    = (float*)(ws + 401408);
    float*    base    = (float*)(ws + 532480);
    float*    bnsum   = (float*)(ws + 663552);
    float*    bnsumsq = (float*)(ws + 663808);
    float*    pmaxf1  = (float*)(ws + 664576);      // 4 MB (32 partials x 32K)
    float*    psum    = (float*)(ws + 664576);      // aliases pmaxf1 (dead after k_cmax)
    u64*      maskp   = (u64*)  (ws + 4858880);     // 4 MB
    ushort_t* hT      = (ushort_t*)(ws + 9053184);  // 4 MB bf16
    __half*   outl2   = (__half*)(ws + 13247488);   // 8 MB (8 slices f16)
    float*    outpre  = (float*)(ws + 21636096);    // 2 MB

    float* out_main = (float*)d_out;
    float* out_gs   = out_main + 524288;

    (void)hipMemsetAsync(bnsum, 0, 512, stream);   // bnsum + bnsumsq
    hipLaunchKernelGGL(k_gs,       dim3(1),    dim3(512), 0, stream,
                       gstate, Wg, W, a1, a2, gamma_g, beta_g, gs, wa1, wa2, out_gs);
    hipLaunchKernelGGL(k_h,        dim3(256),  dim3(256), 0, stream,
                       V, gsize, gs, W, wa1, wa2, hT, f1, f2);
    hipLaunchKernelGGL(k_mask_max, dim3(1024), dim3(256), 0, stream,
                       A, f1, maskp, pmaxf1);
    hipLaunchKernelGGL(k_cmax,     dim3(128),  dim3(256), 0, stream,
                       pmaxf1, f2, colmax);
    hipLaunchKernelGGL(k_colsum,   dim3(512),  dim3(256), 0, stream,
                       maskp, f1, f2, colmax, psum);
    hipLaunchKernelGGL(k_csum,     dim3(128),  dim3(256), 0, stream,
                       psum, colmax, ecol, base);
    hipLaunchKernelGGL(k_pass2,    dim3(512),  dim3(256), 0, stream,
                       hT, maskp, f1, f2, ecol, base, outl2);
    hipLaunchKernelGGL(k_reduce,   dim3(256),  dim3(256), 0, stream,
                       outl2, bias, outpre, bnsum, bnsumsq);
    hipLaunchKernelGGL(k_bnapply,  dim3(128),  dim3(256), 0, stream,
                       outpre, bnsum, bnsumsq, gamma_n, beta_n, out_main);
}

// Round 8
// 143.591 us; speedup vs baseline: 1.7806x; 1.0066x over previous
//
#include <hip/hip_runtime.h>
#include <hip/hip_fp16.h>

typedef unsigned long long u64;
typedef unsigned short ushort_t;
typedef __attribute__((ext_vector_type(8))) short short8v;   // 8 bf16 (4 VGPR)
typedef __attribute__((ext_vector_type(16))) float f32x16;   // MFMA accumulator

#define DI __device__ __forceinline__

DI unsigned cvt_pk_bf16(float lo, float hi) {   // u32 = {bf16(hi)<<16 | bf16(lo)}, RNE
    unsigned r;
    asm volatile("v_cvt_pk_bf16_f32 %0, %1, %2" : "=v"(r) : "v"(lo), "v"(hi));
    return r;
}

// Dims: b=8, N=1024, L=4, C=128, O=64, F=64, C+O=192
// ---------------------------------------------------------------------------
// k_gs: gs = global_state@Wg; gs BN+relu -> out_gs; wa1/wa2[l][c] = W[l][c][:].a{1,2}[l]
__global__ __launch_bounds__(512)
void k_gs(const float* gstate, const float* Wg, const float* W, const float* a1, const float* a2,
          const float* gamma_g, const float* beta_g, float* gs, float* wa1, float* wa2, float* outg)
{
    int t = threadIdx.x;
    int b = t >> 6, o = t & 63;
    float acc = 0.f;
    for (int c = 0; c < 128; ++c)
        acc += gstate[b*128 + c] * Wg[c*64 + o];
    __shared__ float sgs[512];
    __shared__ float mu_s[64], rs_s[64];
    sgs[t] = acc; gs[t] = acc;
    __syncthreads();
    if (t < 64) {
        float s = 0.f, sq = 0.f;
        for (int bb = 0; bb < 8; ++bb) { float v = sgs[bb*64 + t]; s += v; sq += v*v; }
        float mu = s * 0.125f;
        float var = sq * 0.125f - mu*mu;
        mu_s[t] = mu; rs_s[t] = rsqrtf(var + 1e-5f);
    }
    __syncthreads();
    {
        float v = (sgs[t] - mu_s[o]) * rs_s[o] * gamma_g[o] + beta_g[o];
        outg[t] = fmaxf(v, 0.f);
    }
    for (int e = t; e < 768; e += 512) {
        int l = e / 192, c = e - l*192;
        float s1 = 0.f, s2 = 0.f;
        const float* wp = W + (l*192 + c) * 64;
        for (int f = 0; f < 64; ++f) {
            float w = wp[f];
            s1 += w * a1[l*64 + f];
            s2 += w * a2[l*64 + f];
        }
        wa1[e] = s1; wa2[e] = s2;
    }
}

// ---------------------------------------------------------------------------
// k_h: hT[l][b][f][m] (bf16, m=node index) = (Vg @ W[l])^T; f1/f2[l][b][n] = Vg.wa{1,2}[l]
// grid 256 = (b=8) x (nt=32 tiles of 32 rows); block 256
__global__ __launch_bounds__(256)
void k_h(const float* V, const int* gsize, const float* gs, const float* W,
         const float* wa1, const float* wa2, ushort_t* hT, float* f1, float* f2)
{
    int blk = blockIdx.x;
    int b = blk >> 5, nt = blk & 31, n0 = nt * 32;
    int t = threadIdx.x;
    __shared__ float vg[32][194];
    {
        int r = t >> 3, c0 = (t & 7) * 16;
        const float* vp = V + ((size_t)(b*1024 + n0 + r) * 128 + c0);
        float4 v0 = *(const float4*)(vp + 0);
        float4 v1 = *(const float4*)(vp + 4);
        float4 v2 = *(const float4*)(vp + 8);
        float4 v3 = *(const float4*)(vp + 12);
        *(float4*)&vg[r][c0 + 0]  = v0;
        *(float4*)&vg[r][c0 + 4]  = v1;
        *(float4*)&vg[r][c0 + 8]  = v2;
        *(float4*)&vg[r][c0 + 12] = v3;
    }
    {
        int r = t >> 3, o0 = (t & 7) * 8;
        bool on = (n0 + r) < gsize[b];
        for (int j = 0; j < 8; ++j) vg[r][128 + o0 + j] = on ? gs[b*64 + o0 + j] : 0.f;
    }
    __syncthreads();
    int ty = t >> 5, tx = t & 31;
    int r0 = ty * 4;
    int j0 = tx * 8;
    int lw = j0 >> 6, f0 = j0 & 63;
    float acc[4][8];
    for (int i = 0; i < 4; ++i) for (int j = 0; j < 8; ++j) acc[i][j] = 0.f;
    const float* wp = W + (size_t)(lw*192) * 64 + f0;
    for (int c = 0; c < 192; ++c) {
        float4 wl = *(const float4*)(wp + c*64);
        float4 wh = *(const float4*)(wp + c*64 + 4);
        float wf[8] = {wl.x, wl.y, wl.z, wl.w, wh.x, wh.y, wh.z, wh.w};
        float a0 = vg[r0+0][c], a1v = vg[r0+1][c], a2v = vg[r0+2][c], a3v = vg[r0+3][c];
        for (int j = 0; j < 8; ++j) {
            acc[0][j] += a0  * wf[j];
            acc[1][j] += a1v * wf[j];
            acc[2][j] += a2v * wf[j];
            acc[3][j] += a3v * wf[j];
        }
    }
    int lb = lw*8 + b;
    #pragma unroll
    for (int j = 0; j < 8; ++j) {
        uint2 st;
        st.x = cvt_pk_bf16(acc[0][j], acc[1][j]);
        st.y = cvt_pk_bf16(acc[2][j], acc[3][j]);
        *(uint2*)(hT + ((size_t)(lb*64 + f0 + j)) * 1024 + n0 + r0) = st;
    }
    {
        int r = t & 31, l = (t >> 5) & 3, which = t >> 7;
        const float* wl = (which ? wa2 : wa1) + l*192;
        float s = 0.f;
        for (int c = 0; c < 192; ++c) s += vg[r][c] * wl[c];
        float* dst = which ? f2 : f1;
        dst[(l*8 + b) * 1024 + n0 + r] = s;
    }
}

// ---------------------------------------------------------------------------
// k_mask_max v4: LANE-LOCAL PACKING, no ballot. Lane owns 16 consecutive columns
// (m = lane*16+j) via 4x float4 loads; packs a u16 mask word (bit j) and updates
// lane-local column max mx[j]. u16-lane layout is bit-identical to the u64 mask
// layout consumers already use. 2-row software pipeline for 8KB in flight/wave.
// grid 1024 = b(8) x l(4) x nc(32 chunks of 32 rows); block 256 (4 waves x 8 rows)
__global__ __launch_bounds__(256)
void k_mask_max(const float* A, const float* f1, u64* maskp, float* pmaxf1)
{
    int blk = blockIdx.x;
    int nc = blk & 31, l = (blk >> 5) & 3, b = blk >> 7;
    int t = threadIdx.x;
    int wv = t >> 6, lane = t & 63;
    int lb = l*8 + b;
    int n0 = nc*32 + wv*8;
    const float* f1p = f1 + lb*1024;
    ushort_t* mp16 = (ushort_t*)maskp;
    float mx[16];
    #pragma unroll
    for (int j = 0; j < 16; ++j) mx[j] = -3.0e38f;

    const float* Ap = A + (((size_t)(b*1024 + n0) * 4 + l) * 1024) + lane*16;
    float4 c0 = *(const float4*)(Ap + 0);
    float4 c1 = *(const float4*)(Ap + 4);
    float4 c2 = *(const float4*)(Ap + 8);
    float4 c3 = *(const float4*)(Ap + 12);
    #pragma unroll
    for (int r = 0; r < 8; ++r) {
        float va[16] = {c0.x,c0.y,c0.z,c0.w, c1.x,c1.y,c1.z,c1.w,
                        c2.x,c2.y,c2.z,c2.w, c3.x,c3.y,c3.z,c3.w};
        if (r < 7) {   // prefetch next row (stride 4096 floats)
            const float* An = Ap + (size_t)(r + 1) * 4096;
            c0 = *(const float4*)(An + 0);
            c1 = *(const float4*)(An + 4);
            c2 = *(const float4*)(An + 8);
            c3 = *(const float4*)(An + 12);
        }
        float f1n = f1p[n0 + r];
        unsigned bits = 0;
        #pragma unroll
        for (int j = 0; j < 16; ++j) {
            bool pos = va[j] > 0.f;
            bits |= pos ? (1u << j) : 0u;
            mx[j] = fmaxf(mx[j], pos ? f1n : -3.0e38f);
        }
        mp16[(((size_t)(b*1024 + n0 + r) * 4 + l) << 6) + lane] = (ushort_t)bits;
    }
    // block-reduce the 4 waves' column maxima -> pmaxf1[nc][lb*1024 + m]
    __shared__ float mxs[4][64][17];   // pad 17: conflict-free scalar access
    #pragma unroll
    for (int j = 0; j < 16; ++j) mxs[wv][lane][j] = mx[j];
    __syncthreads();
    #pragma unroll
    for (int q = 0; q < 4; ++q) {
        int m = q*256 + t;             // column index 0..1023
        int l2 = m >> 4, j = m & 15;
        float v = fmaxf(fmaxf(mxs[0][l2][j], mxs[1][l2][j]),
                        fmaxf(mxs[2][l2][j], mxs[3][l2][j]));
        pmaxf1[(size_t)nc*32768 + lb*1024 + m] = v;
    }
}

// ---------------------------------------------------------------------------
// k_cmax: colmax[lbm] = empty ? -9e15 : leaky(f2 + max over 32 partials)
__global__ __launch_bounds__(256)
void k_cmax(const float* pmaxf1, const float* f2, float* colmax)
{
    int i = blockIdx.x * 256 + threadIdx.x;   // 32768
    float mx = pmaxf1[i];
    #pragma unroll
    for (int k = 1; k < 32; ++k) mx = fmaxf(mx, pmaxf1[k*32768 + i]);
    float e = f2[i] + mx;
    e = e > 0.f ? e : 0.2f * e;
    colmax[i] = (mx < -1e38f) ? -9e15f : e;
}

// ---------------------------------------------------------------------------
// k_colsum: psum[nc][lbm] = sum_n exp((mask? e : NEG) - colmax)
// grid 512 = l(4) x b(8) x mc(4) x nc(4); block 256 (1 col/thread)
__global__ __launch_bounds__(256)
void k_colsum(const u64* maskp, const float* f1, const float* f2, const float* colmax, float* psum)
{
    int blk = blockIdx.x;
    int nc = blk & 3, mc = (blk >> 2) & 3, b = (blk >> 4) & 7, l = blk >> 7;
    int t = threadIdx.x;
    int lb = l*8 + b;
    int m = mc*256 + t;
    int n0 = nc*256;
    __shared__ float f1s[256];
    __shared__ u64 wlds[1024];
    f1s[t] = f1[lb*1024 + n0 + t];
    for (int k = 0; k < 4; ++k) {
        int e = t + k*256;
        int n = e >> 2, ws_ = e & 3;
        wlds[e] = maskp[((size_t)(b*1024 + n0 + n) * 4 + l) * 16 + mc*4 + ws_];
    }
    __syncthreads();
    float f2v = f2[lb*1024 + m];
    float cm  = colmax[lb*1024 + m];
    int wv = t >> 6;
    int bit = t & 63;
    float s = 0.f;
    #pragma unroll 4
    for (int n = 0; n < 256; ++n) {
        u64 word = wlds[n*4 + wv];
        float e1 = f1s[n] + f2v;
        e1 = e1 > 0.f ? e1 : 0.2f * e1;
        float v = ((word >> bit) & 1) ? e1 : -9e15f;
        s += __expf(v - cm);
    }
    psum[nc*32768 + lb*1024 + m] = s;
}

// ---------------------------------------------------------------------------
// k_csum: ecol = empty?0:exp(-colmax)/s; base = empty? 1/s : 0
__global__ __launch_bounds__(256)
void k_csum(const float* psum, const float* colmax, float* ecol, float* base)
{
    int i = blockIdx.x * 256 + threadIdx.x;
    float s = psum[i] + psum[32768 + i] + psum[65536 + i] + psum[98304 + i];
    float rs = 1.f / s;
    float cm = colmax[i];
    bool emp = (cm == -9e15f);
    ecol[i] = emp ? 0.f : __expf(-cm) * rs;
    base[i] = emp ? rs : 0.f;
}

// ---------------------------------------------------------------------------
// k_pass2: MFMA. outl2[sl=ks*4+l][b][n][f] (f16) = sum_{m in K-half} att[n,m]*h[m,f]
// att generated in registers in A-frag layout: row=lane&31, k=8*(lane>>5)+i.
// grid 512 = ks(2) x l(4) x b(8) x nt(8 tiles of 128 n-rows); block 256 (4 waves: 32n x 64f each)
__global__ __launch_bounds__(256)
void k_pass2(const ushort_t* hT, const u64* maskp, const float* f1,
             const float* f2, const float* ecol, const float* base, __half* outl2)
{
    int blk = blockIdx.x;
    int nt = blk & 7, b = (blk >> 3) & 7, l = (blk >> 6) & 3, ks = blk >> 8;
    int lb = l*8 + b;
    int n0 = nt*128;
    int m0 = ks*512;
    int t = threadIdx.x;
    int w = t >> 6, lane = t & 63;
    int rl = lane & 31, kg = lane >> 5;

    __shared__ float f2t[512], ect[512], bat[512];
    __shared__ ushort_t hl[64][72];   // 64 f x 64 m bf16 chunk, pad 72

    for (int k = 0; k < 2; ++k) {
        int j = t + k*256;
        f2t[j] = f2[lb*1024 + m0 + j];
        ect[j] = ecol[lb*1024 + m0 + j];
        bat[j] = base[lb*1024 + m0 + j];
    }
    int nrow = n0 + w*32 + rl;
    float f1v = f1[lb*1024 + nrow];
    const u64* mrow = maskp + ((size_t)(b*1024 + nrow)*4 + l)*16 + ks*8;

    f32x16 acc0 = {0,0,0,0,0,0,0,0,0,0,0,0,0,0,0,0};
    f32x16 acc1 = {0,0,0,0,0,0,0,0,0,0,0,0,0,0,0,0};

    int hf = t >> 2, hseg = t & 3;
    const ushort_t* hsrc = hT + ((size_t)(lb*64 + hf)) * 1024 + m0 + hseg*16;

    for (int kc = 0; kc < 8; ++kc) {
        __syncthreads();
        {   // stage 64f x 64m bf16 chunk
            const uint4* s = (const uint4*)(hsrc + kc*64);
            uint4 q0 = s[0], q1 = s[1];
            *(uint4*)&hl[hf][hseg*16]     = q0;
            *(uint4*)&hl[hf][hseg*16 + 8] = q1;
        }
        u64 wm = mrow[kc];
        __syncthreads();
        #pragma unroll
        for (int kk = 0; kk < 4; ++kk) {
            int jb = kc*64 + kk*16 + kg*8;
            float4 fa = *(float4*)&f2t[jb];
            float4 fb = *(float4*)&f2t[jb+4];
            float4 ea = *(float4*)&ect[jb];
            float4 eb = *(float4*)&ect[jb+4];
            float4 ba = *(float4*)&bat[jb];
            float4 bb = *(float4*)&bat[jb+4];
            unsigned mb = (unsigned)(wm >> (kk*16 + kg*8)) & 0xffu;
            float xs[8] = {fa.x,fa.y,fa.z,fa.w,fb.x,fb.y,fb.z,fb.w};
            float es[8] = {ea.x,ea.y,ea.z,ea.w,eb.x,eb.y,eb.z,eb.w};
            float bs[8] = {ba.x,ba.y,ba.z,ba.w,bb.x,bb.y,bb.z,bb.w};
            float av[8];
            #pragma unroll
            for (int i = 0; i < 8; ++i) {
                float x = f1v + xs[i];
                x = fmaxf(x, 0.2f * x);          // leaky_relu(0.2)
                float p = __expf(x) * es[i];
                av[i] = (mb & (1u << i)) ? p : bs[i];
            }
            union { unsigned u[4]; short8v s; } af;
            af.u[0] = cvt_pk_bf16(av[0], av[1]);
            af.u[1] = cvt_pk_bf16(av[2], av[3]);
            af.u[2] = cvt_pk_bf16(av[4], av[5]);
            af.u[3] = cvt_pk_bf16(av[6], av[7]);
            short8v b0 = *(short8v*)&hl[rl][kk*16 + kg*8];
            short8v b1 = *(short8v*)&hl[32 + rl][kk*16 + kg*8];
            acc0 = __builtin_amdgcn_mfma_f32_32x32x16_bf16(af.s, b0, acc0, 0, 0, 0);
            acc1 = __builtin_amdgcn_mfma_f32_32x32x16_bf16(af.s, b1, acc1, 0, 0, 0);
        }
    }
    int sl = ks*4 + l;
    __half* op = outl2 + ((size_t)(sl*8 + b) * 1024) * 64;
    #pragma unroll
    for (int r = 0; r < 16; ++r) {
        int row = n0 + w*32 + (r & 3) + 8*(r >> 2) + 4*kg;   // C/D layout (m74/m101)
        op[(size_t)row*64 + rl]      = __float2half(acc0[r]);
        op[(size_t)row*64 + 32 + rl] = __float2half(acc1[r]);
    }
}

// ---------------------------------------------------------------------------
// k_reduce: outpre = sum_{8 slices} outl2 + bias; BN partial sums (LDS + global atomics)
// grid 256 x 256 thr x 8 elems = 524288
__global__ __launch_bounds__(256)
void k_reduce(const __half* outl2, const float* bias, float* outpre, float* bnsum, float* bnsumsq)
{
    int blk = blockIdx.x, t = threadIdx.x;
    __shared__ float red[2][64];
    if (t < 128) red[t >> 6][t & 63] = 0.f;
    __syncthreads();
    size_t idx = (size_t)blk * 2048 + t * 8;
    int fb = (t * 8) & 63;
    float o[8];
    for (int j = 0; j < 8; ++j) o[j] = bias[fb + j];
    #pragma unroll
    for (int sl = 0; sl < 8; ++sl) {
        uint4 u = *(const uint4*)(outl2 + (size_t)sl * 524288 + idx);
        const __half* hh = (const __half*)&u;
        #pragma unroll
        for (int j = 0; j < 8; ++j) o[j] += __half2float(hh[j]);
    }
    *(float4*)(outpre + idx)     = make_float4(o[0], o[1], o[2], o[3]);
    *(float4*)(outpre + idx + 4) = make_float4(o[4], o[5], o[6], o[7]);
    for (int j = 0; j < 8; ++j) {
        atomicAdd(&red[0][fb + j], o[j]);
        atomicAdd(&red[1][fb + j], o[j]*o[j]);
    }
    __syncthreads();
    if (t < 64) { atomicAdd(&bnsum[t], red[0][t]); atomicAdd(&bnsumsq[t], red[1][t]); }
}

// ---------------------------------------------------------------------------
// grid 128 (covers exactly 524288 output elems)
__global__ __launch_bounds__(256)
void k_bnapply(const float* outpre, const float* bnsum, const float* bnsumsq,
               const float* gamma, const float* beta, float* out)
{
    int blk = blockIdx.x, t = threadIdx.x;
    int f0 = (t * 4) & 63;
    float mu[4], rstd[4], ga[4], be[4];
    for (int j = 0; j < 4; ++j) {
        float sm = bnsum[f0 + j], sq = bnsumsq[f0 + j];
        float m = sm * (1.f / 8192.f);
        float var = sq * (1.f / 8192.f) - m*m;
        mu[j] = m; rstd[j] = rsqrtf(var + 1e-5f);
        ga[j] = gamma[f0 + j]; be[j] = beta[f0 + j];
    }
    for (int g = 0; g < 4; ++g) {
        size_t base = (size_t)blk * 4096 + g * 1024 + t * 4;
        float4 v = *(const float4*)(outpre + base);
        float x[4] = {v.x, v.y, v.z, v.w};
        float y[4];
        for (int j = 0; j < 4; ++j) {
            float z = (x[j] - mu[j]) * rstd[j] * ga[j] + be[j];
            y[j] = fmaxf(z, 0.f);
        }
        *(float4*)(out + base) = make_float4(y[0], y[1], y[2], y[3]);
    }
}

// ---------------------------------------------------------------------------
extern "C" void kernel_launch(void* const* d_in, const int* in_sizes, int n_in,
                              void* d_out, int out_size, void* d_ws, size_t ws_size,
                              hipStream_t stream)
{
    const float* V       = (const float*)d_in[0];
    const float* A       = (const float*)d_in[1];
    const float* gstate  = (const float*)d_in[2];
    const int*   gsize   = (const int*)d_in[3];
    // d_in[4] subgraph_size: unused by reference
    const float* Wg      = (const float*)d_in[5];
    const float* W       = (const float*)d_in[6];
    const float* a1      = (const float*)d_in[7];
    const float* a2      = (const float*)d_in[8];
    const float* bias    = (const float*)d_in[9];
    const float* gamma_n = (const float*)d_in[10];
    const float* beta_n  = (const float*)d_in[11];
    const float* gamma_g = (const float*)d_in[12];
    const float* beta_g  = (const float*)d_in[13];

    char* ws = (char*)d_ws;               // ~22.6 MB used
    float*    gs      = (float*)(ws + 0);
    float*    wa1     = (float*)(ws + 2048);
    float*    wa2     = (float*)(ws + 5120);
    float*    f1      = (float*)(ws + 8192);
    float*    f2      = (float*)(ws + 139264);
    float*    colmax  = (float*)(ws + 270336);
    float*    ecol    = (float*)(ws + 401408);
    float*    base    = (float*)(ws + 532480);
    float*    bnsum   = (float*)(ws + 663552);
    float*    bnsumsq = (float*)(ws + 663808);
    float*    pmaxf1  = (float*)(ws + 664576);      // 4 MB (32 partials x 32K)
    float*    psum    = (float*)(ws + 664576);      // aliases pmaxf1 (dead after k_cmax)
    u64*      maskp   = (u64*)  (ws + 4858880);     // 4 MB
    ushort_t* hT      = (ushort_t*)(ws + 9053184);  // 4 MB bf16
    __half*   outl2   = (__half*)(ws + 13247488);   // 8 MB (8 slices f16)
    float*    outpre  = (float*)(ws + 21636096);    // 2 MB

    float* out_main = (float*)d_out;
    float* out_gs   = out_main + 524288;

    (void)hipMemsetAsync(bnsum, 0, 512, stream);   // bnsum + bnsumsq
    hipLaunchKernelGGL(k_gs,       dim3(1),    dim3(512), 0, stream,
                       gstate, Wg, W, a1, a2, gamma_g, beta_g, gs, wa1, wa2, out_gs);
    hipLaunchKernelGGL(k_h,        dim3(256),  dim3(256), 0, stream,
                       V, gsize, gs, W, wa1, wa2, hT, f1, f2);
    hipLaunchKernelGGL(k_mask_max, dim3(1024), dim3(256), 0, stream,
                       A, f1, maskp, pmaxf1);
    hipLaunchKernelGGL(k_cmax,     dim3(128),  dim3(256), 0, stream,
                       pmaxf1, f2, colmax);
    hipLaunchKernelGGL(k_colsum,   dim3(512),  dim3(256), 0, stream,
                       maskp, f1, f2, colmax, psum);
    hipLaunchKernelGGL(k_csum,     dim3(128),  dim3(256), 0, stream,
                       psum, colmax, ecol, base);
    hipLaunchKernelGGL(k_pass2,    dim3(512),  dim3(256), 0, stream,
                       hT, maskp, f1, f2, ecol, base, outl2);
    hipLaunchKernelGGL(k_reduce,   dim3(256),  dim3(256), 0, stream,
                       outl2, bias, outpre, bnsum, bnsumsq);
    hipLaunchKernelGGL(k_bnapply,  dim3(128),  dim3(256), 0, stream,
                       outpre, bnsum, bnsumsq, gamma_n, beta_n, out_main);
}

// Round 10
// 129.847 us; speedup vs baseline: 1.9690x; 1.1058x over previous
//
#include <hip/hip_runtime.h>
#include <hip/hip_fp16.h>

typedef unsigned long long u64;
typedef unsigned short ushort_t;
typedef __attribute__((ext_vector_type(8))) short short8v;   // 8 bf16 (4 VGPR)
typedef __attribute__((ext_vector_type(16))) float f32x16;   // MFMA accumulator

#define DI __device__ __forceinline__

DI unsigned cvt_pk_bf16(float lo, float hi) {   // u32 = {bf16(hi)<<16 | bf16(lo)}, RNE
    unsigned r;
    asm volatile("v_cvt_pk_bf16_f32 %0, %1, %2" : "=v"(r) : "v"(lo), "v"(hi));
    return r;
}

// Dims: b=8, N=1024, L=4, C=128, O=64, F=64, C+O=192
// Softmax reference constant: K[m] = leaky(f2[m]) + 12 (any per-column constant
// cancels in exp(e-K)/sum exp(e'-K); 12 keeps all exponents in-range).
// ---------------------------------------------------------------------------
// k_h: fused. Per block: gs[b] = gstate[b]@Wg (LDS), wa1/wa2 = W@a (LDS), then
// hT[l][b][f][m] (bf16) = (Vg @ W[l])^T and f1/f2[l][b][n] = Vg.wa{1,2}[l].
// grid 256 = (b=8) x (nt=32 tiles of 32 rows); block 256
__global__ __launch_bounds__(256)
void k_h(const float* V, const int* gsize, const float* gstate, const float* Wg,
         const float* W, const float* a1, const float* a2,
         ushort_t* hT, float* f1, float* f2)
{
    int blk = blockIdx.x;
    int b = blk >> 5, nt = blk & 31, n0 = nt * 32;
    int t = threadIdx.x;
    __shared__ float gss[64];
    __shared__ float was[2][4][192];   // 6 KB
    __shared__ float vg[32][194];
    // phase 0: wave0 computes gs; waves 1-3 compute wa1/wa2 (1536 dots / 192 thr = 8 each)
    if (t < 64) {
        float acc = 0.f;
        for (int c = 0; c < 128; ++c) acc += gstate[b*128 + c] * Wg[c*64 + t];
        gss[t] = acc;
    } else {
        int tt = t - 64;
        #pragma unroll
        for (int k = 0; k < 8; ++k) {
            int e = tt + k*192;                    // 0..1535
            int which = (e >= 768) ? 1 : 0;
            int idx = which ? e - 768 : e;
            int l = idx / 192, c = idx - l*192;
            const float* ap = (which ? a2 : a1) + l*64;
            const float* wp = W + (l*192 + c) * 64;
            float s = 0.f;
            for (int f = 0; f < 64; ++f) s += wp[f] * ap[f];
            was[which][l][c] = s;
        }
    }
    __syncthreads();
    {
        int r = t >> 3, c0 = (t & 7) * 16;
        const float* vp = V + ((size_t)(b*1024 + n0 + r) * 128 + c0);
        float4 v0 = *(const float4*)(vp + 0);
        float4 v1 = *(const float4*)(vp + 4);
        float4 v2 = *(const float4*)(vp + 8);
        float4 v3 = *(const float4*)(vp + 12);
        *(float4*)&vg[r][c0 + 0]  = v0;
        *(float4*)&vg[r][c0 + 4]  = v1;
        *(float4*)&vg[r][c0 + 8]  = v2;
        *(float4*)&vg[r][c0 + 12] = v3;
    }
    {
        int r = t >> 3, o0 = (t & 7) * 8;
        bool on = (n0 + r) < gsize[b];
        for (int j = 0; j < 8; ++j) vg[r][128 + o0 + j] = on ? gss[o0 + j] : 0.f;
    }
    __syncthreads();
    int ty = t >> 5, tx = t & 31;
    int r0 = ty * 4;
    int j0 = tx * 8;
    int lw = j0 >> 6, f0 = j0 & 63;
    float acc[4][8];
    for (int i = 0; i < 4; ++i) for (int j = 0; j < 8; ++j) acc[i][j] = 0.f;
    const float* wp = W + (size_t)(lw*192) * 64 + f0;
    for (int c = 0; c < 192; ++c) {
        float4 wl = *(const float4*)(wp + c*64);
        float4 wh = *(const float4*)(wp + c*64 + 4);
        float wf[8] = {wl.x, wl.y, wl.z, wl.w, wh.x, wh.y, wh.z, wh.w};
        float a0 = vg[r0+0][c], a1v = vg[r0+1][c], a2v = vg[r0+2][c], a3v = vg[r0+3][c];
        for (int j = 0; j < 8; ++j) {
            acc[0][j] += a0  * wf[j];
            acc[1][j] += a1v * wf[j];
            acc[2][j] += a2v * wf[j];
            acc[3][j] += a3v * wf[j];
        }
    }
    int lb = lw*8 + b;
    #pragma unroll
    for (int j = 0; j < 8; ++j) {
        uint2 st;
        st.x = cvt_pk_bf16(acc[0][j], acc[1][j]);
        st.y = cvt_pk_bf16(acc[2][j], acc[3][j]);
        *(uint2*)(hT + ((size_t)(lb*64 + f0 + j)) * 1024 + n0 + r0) = st;
    }
    {
        int r = t & 31, l = (t >> 5) & 3, which = t >> 7;
        const float* wl = &was[which][l][0];
        float s = 0.f;
        for (int c = 0; c < 192; ++c) s += vg[r][c] * wl[c];
        float* dst = which ? f2 : f1;
        dst[(l*8 + b) * 1024 + n0 + r] = s;
    }
}

// ---------------------------------------------------------------------------
// k_maskcolsum: ONE pass over A -> u16 mask words (bit j, column m=lane*16+j;
// layout bit-identical to u64 consumer layout) AND per-column partial
// sum_n exp((mask? leaky(f1+f2) : -inf) - K[m]). Per-wave register partials are
// BLOCK-REDUCED via LDS before one coalesced store (round-9 bug: 4 waves raced
// on the same psum address, dropping 3/4 of rows).
// grid 2048 = b(8) x l(4) x nc(64 chunks of 16 rows); block 256 (4 waves x 4 rows)
__global__ __launch_bounds__(256)
void k_maskcolsum(const float* A, const float* f1, const float* f2,
                  u64* maskp, float* psum)
{
    int blk = blockIdx.x;
    int nc = blk & 63, l = (blk >> 6) & 3, b = blk >> 8;
    int t = threadIdx.x;
    int wv = t >> 6, lane = t & 63;
    int lb = l*8 + b;
    int n0 = nc*16 + wv*4;
    ushort_t* mp16 = (ushort_t*)maskp;

    // lane's 16 columns: K[j] = leaky(f2[m]) + 12; keep f2 in registers too
    float K[16], F2[16];
    {
        const float* f2p = f2 + lb*1024 + lane*16;
        #pragma unroll
        for (int q = 0; q < 4; ++q) {
            float4 v = *(const float4*)(f2p + q*4);
            float x[4] = {v.x, v.y, v.z, v.w};
            #pragma unroll
            for (int i = 0; i < 4; ++i) {
                F2[q*4 + i] = x[i];
                K[q*4 + i]  = fmaxf(x[i], 0.2f*x[i]) + 12.f;
            }
        }
    }
    float s[16];
    #pragma unroll
    for (int j = 0; j < 16; ++j) s[j] = 0.f;

    const float* Ap = A + (((size_t)(b*1024 + n0) * 4 + l) * 1024) + lane*16;
    const float* f1p = f1 + lb*1024;
    float4 c0 = *(const float4*)(Ap + 0);
    float4 c1 = *(const float4*)(Ap + 4);
    float4 c2 = *(const float4*)(Ap + 8);
    float4 c3 = *(const float4*)(Ap + 12);
    #pragma unroll
    for (int r = 0; r < 4; ++r) {
        float va[16] = {c0.x,c0.y,c0.z,c0.w, c1.x,c1.y,c1.z,c1.w,
                        c2.x,c2.y,c2.z,c2.w, c3.x,c3.y,c3.z,c3.w};
        if (r < 3) {   // prefetch next row (stride 4096 floats)
            const float* An = Ap + (size_t)(r + 1) * 4096;
            c0 = *(const float4*)(An + 0);
            c1 = *(const float4*)(An + 4);
            c2 = *(const float4*)(An + 8);
            c3 = *(const float4*)(An + 12);
        }
        float f1n = f1p[n0 + r];
        unsigned bits = 0;
        #pragma unroll
        for (int j = 0; j < 16; ++j) {
            bool pos = va[j] > 0.f;
            bits |= pos ? (1u << j) : 0u;
            float x = f1n + F2[j];
            x = fmaxf(x, 0.2f * x);          // leaky_relu(0.2)
            float p = __expf(x - K[j]);
            s[j] += pos ? p : 0.f;
        }
        mp16[(((size_t)(b*1024 + n0 + r) * 4 + l) << 6) + lane] = (ushort_t)bits;
    }
    // block-reduce the 4 waves' partial sums -> psum[nc][lb*1024 + m]
    __shared__ float ss[4][64][17];   // pad 17: conflict-free scalar access
    #pragma unroll
    for (int j = 0; j < 16; ++j) ss[wv][lane][j] = s[j];
    __syncthreads();
    #pragma unroll
    for (int q = 0; q < 4; ++q) {
        int m = q*256 + t;             // column index 0..1023
        int l2 = m >> 4, j = m & 15;
        float v = (ss[0][l2][j] + ss[1][l2][j]) + (ss[2][l2][j] + ss[3][l2][j]);
        psum[(size_t)nc*32768 + lb*1024 + m] = v;
    }
}

// ---------------------------------------------------------------------------
// k_csum: s = sum of 64 partials; empty col <=> s==0 (every present addend
// >= exp(-40), far above denormal range); ecol = exp(-K)/s; base = empty ? 1/1024 : 0
__global__ __launch_bounds__(256)
void k_csum(const float* psum, const float* f2, float* ecol, float* base)
{
    int i = blockIdx.x * 256 + threadIdx.x;   // 32768
    float s = 0.f;
    #pragma unroll
    for (int k = 0; k < 64; ++k) s += psum[(size_t)k*32768 + i];
    float x = f2[i];
    float K = fmaxf(x, 0.2f*x) + 12.f;
    bool emp = (s == 0.f);
    ecol[i] = emp ? 0.f : __expf(-K) / s;
    base[i] = emp ? (1.f/1024.f) : 0.f;
}

// ---------------------------------------------------------------------------
// k_pass2: MFMA. outl2[sl=ks*4+l][b][n][f] (f16) = sum_{m in K-half} att[n,m]*h[m,f]
// att generated in registers in A-frag layout: row=lane&31, k=8*(lane>>5)+i.
// grid 512 = ks(2) x l(4) x b(8) x nt(8 tiles of 128 n-rows); block 256 (4 waves: 32n x 64f each)
__global__ __launch_bounds__(256)
void k_pass2(const ushort_t* hT, const u64* maskp, const float* f1,
             const float* f2, const float* ecol, const float* base, __half* outl2)
{
    int blk = blockIdx.x;
    int nt = blk & 7, b = (blk >> 3) & 7, l = (blk >> 6) & 3, ks = blk >> 8;
    int lb = l*8 + b;
    int n0 = nt*128;
    int m0 = ks*512;
    int t = threadIdx.x;
    int w = t >> 6, lane = t & 63;
    int rl = lane & 31, kg = lane >> 5;

    __shared__ float f2t[512], ect[512], bat[512];
    __shared__ ushort_t hl[64][72];   // 64 f x 64 m bf16 chunk, pad 72

    for (int k = 0; k < 2; ++k) {
        int j = t + k*256;
        f2t[j] = f2[lb*1024 + m0 + j];
        ect[j] = ecol[lb*1024 + m0 + j];
        bat[j] = base[lb*1024 + m0 + j];
    }
    int nrow = n0 + w*32 + rl;
    float f1v = f1[lb*1024 + nrow];
    const u64* mrow = maskp + ((size_t)(b*1024 + nrow)*4 + l)*16 + ks*8;

    f32x16 acc0 = {0,0,0,0,0,0,0,0,0,0,0,0,0,0,0,0};
    f32x16 acc1 = {0,0,0,0,0,0,0,0,0,0,0,0,0,0,0,0};

    int hf = t >> 2, hseg = t & 3;
    const ushort_t* hsrc = hT + ((size_t)(lb*64 + hf)) * 1024 + m0 + hseg*16;

    for (int kc = 0; kc < 8; ++kc) {
        __syncthreads();
        {   // stage 64f x 64m bf16 chunk
            const uint4* s = (const uint4*)(hsrc + kc*64);
            uint4 q0 = s[0], q1 = s[1];
            *(uint4*)&hl[hf][hseg*16]     = q0;
            *(uint4*)&hl[hf][hseg*16 + 8] = q1;
        }
        u64 wm = mrow[kc];
        __syncthreads();
        #pragma unroll
        for (int kk = 0; kk < 4; ++kk) {
            int jb = kc*64 + kk*16 + kg*8;
            float4 fa = *(float4*)&f2t[jb];
            float4 fb = *(float4*)&f2t[jb+4];
            float4 ea = *(float4*)&ect[jb];
            float4 eb = *(float4*)&ect[jb+4];
            float4 ba = *(float4*)&bat[jb];
            float4 bb = *(float4*)&bat[jb+4];
            unsigned mb = (unsigned)(wm >> (kk*16 + kg*8)) & 0xffu;
            float xs[8] = {fa.x,fa.y,fa.z,fa.w,fb.x,fb.y,fb.z,fb.w};
            float es[8] = {ea.x,ea.y,ea.z,ea.w,eb.x,eb.y,eb.z,eb.w};
            float bs[8] = {ba.x,ba.y,ba.z,ba.w,bb.x,bb.y,bb.z,bb.w};
            float av[8];
            #pragma unroll
            for (int i = 0; i < 8; ++i) {
                float x = f1v + xs[i];
                x = fmaxf(x, 0.2f * x);          // leaky_relu(0.2)
                float p = __expf(x) * es[i];
                av[i] = (mb & (1u << i)) ? p : bs[i];
            }
            union { unsigned u[4]; short8v s; } af;
            af.u[0] = cvt_pk_bf16(av[0], av[1]);
            af.u[1] = cvt_pk_bf16(av[2], av[3]);
            af.u[2] = cvt_pk_bf16(av[4], av[5]);
            af.u[3] = cvt_pk_bf16(av[6], av[7]);
            short8v b0 = *(short8v*)&hl[rl][kk*16 + kg*8];
            short8v b1 = *(short8v*)&hl[32 + rl][kk*16 + kg*8];
            acc0 = __builtin_amdgcn_mfma_f32_32x32x16_bf16(af.s, b0, acc0, 0, 0, 0);
            acc1 = __builtin_amdgcn_mfma_f32_32x32x16_bf16(af.s, b1, acc1, 0, 0, 0);
        }
    }
    int sl = ks*4 + l;
    __half* op = outl2 + ((size_t)(sl*8 + b) * 1024) * 64;
    #pragma unroll
    for (int r = 0; r < 16; ++r) {
        int row = n0 + w*32 + (r & 3) + 8*(r >> 2) + 4*kg;   // C/D layout (m74/m101)
        op[(size_t)row*64 + rl]      = __float2half(acc0[r]);
        op[(size_t)row*64 + 32 + rl] = __float2half(acc1[r]);
    }
}

// ---------------------------------------------------------------------------
// k_reduce: outpre = sum_{8 slices} outl2 + bias; BN partial sums (LDS + global atomics)
// grid 256 x 256 thr x 8 elems = 524288
__global__ __launch_bounds__(256)
void k_reduce(const __half* outl2, const float* bias, float* outpre, float* bnsum, float* bnsumsq)
{
    int blk = blockIdx.x, t = threadIdx.x;
    __shared__ float red[2][64];
    if (t < 128) red[t >> 6][t & 63] = 0.f;
    __syncthreads();
    size_t idx = (size_t)blk * 2048 + t * 8;
    int fb = (t * 8) & 63;
    float o[8];
    for (int j = 0; j < 8; ++j) o[j] = bias[fb + j];
    #pragma unroll
    for (int sl = 0; sl < 8; ++sl) {
        uint4 u = *(const uint4*)(outl2 + (size_t)sl * 524288 + idx);
        const __half* hh = (const __half*)&u;
        #pragma unroll
        for (int j = 0; j < 8; ++j) o[j] += __half2float(hh[j]);
    }
    *(float4*)(outpre + idx)     = make_float4(o[0], o[1], o[2], o[3]);
    *(float4*)(outpre + idx + 4) = make_float4(o[4], o[5], o[6], o[7]);
    for (int j = 0; j < 8; ++j) {
        atomicAdd(&red[0][fb + j], o[j]);
        atomicAdd(&red[1][fb + j], o[j]*o[j]);
    }
    __syncthreads();
    if (t < 64) { atomicAdd(&bnsum[t], red[0][t]); atomicAdd(&bnsumsq[t], red[1][t]); }
}

// ---------------------------------------------------------------------------
// k_bnapply: main BN+relu (grid 128 covers 524288 elems). Block 0 additionally
// computes gs = gstate@Wg, its batch BN+relu -> out_gs (replaces old k_gs).
__global__ __launch_bounds__(256)
void k_bnapply(const float* outpre, const float* bnsum, const float* bnsumsq,
               const float* gamma, const float* beta, float* out,
               const float* gstate, const float* Wg,
               const float* gamma_g, const float* beta_g, float* out_gs)
{
    int blk = blockIdx.x, t = threadIdx.x;
    __shared__ float gsa[512];
    __shared__ float gmu[64], grs[64];
    if (blk == 0) {
        for (int p = t; p < 512; p += 256) {
            int bb = p >> 6, o = p & 63;
            float acc = 0.f;
            for (int c = 0; c < 128; ++c) acc += gstate[bb*128 + c] * Wg[c*64 + o];
            gsa[p] = acc;
        }
        __syncthreads();
        if (t < 64) {
            float s = 0.f, sq = 0.f;
            for (int bb = 0; bb < 8; ++bb) { float v = gsa[bb*64 + t]; s += v; sq += v*v; }
            float mu = s * 0.125f;
            float var = sq * 0.125f - mu*mu;
            gmu[t] = mu; grs[t] = rsqrtf(var + 1e-5f);
        }
        __syncthreads();
        for (int p = t; p < 512; p += 256) {
            int o = p & 63;
            float v = (gsa[p] - gmu[o]) * grs[o] * gamma_g[o] + beta_g[o];
            out_gs[p] = fmaxf(v, 0.f);
        }
    }
    int f0 = (t * 4) & 63;
    float mu[4], rstd[4], ga[4], be[4];
    for (int j = 0; j < 4; ++j) {
        float sm = bnsum[f0 + j], sq = bnsumsq[f0 + j];
        float m = sm * (1.f / 8192.f);
        float var = sq * (1.f / 8192.f) - m*m;
        mu[j] = m; rstd[j] = rsqrtf(var + 1e-5f);
        ga[j] = gamma[f0 + j]; be[j] = beta[f0 + j];
    }
    for (int g = 0; g < 4; ++g) {
        size_t base = (size_t)blk * 4096 + g * 1024 + t * 4;
        float4 v = *(const float4*)(outpre + base);
        float x[4] = {v.x, v.y, v.z, v.w};
        float y[4];
        for (int j = 0; j < 4; ++j) {
            float z = (x[j] - mu[j]) * rstd[j] * ga[j] + be[j];
            y[j] = fmaxf(z, 0.f);
        }
        *(float4*)(out + base) = make_float4(y[0], y[1], y[2], y[3]);
    }
}

// ---------------------------------------------------------------------------
extern "C" void kernel_launch(void* const* d_in, const int* in_sizes, int n_in,
                              void* d_out, int out_size, void* d_ws, size_t ws_size,
                              hipStream_t stream)
{
    const float* V       = (const float*)d_in[0];
    const float* A       = (const float*)d_in[1];
    const float* gstate  = (const float*)d_in[2];
    const int*   gsize   = (const int*)d_in[3];
    // d_in[4] subgraph_size: unused by reference
    const float* Wg      = (const float*)d_in[5];
    const float* W       = (const float*)d_in[6];
    const float* a1      = (const float*)d_in[7];
    const float* a2      = (const float*)d_in[8];
    const float* bias    = (const float*)d_in[9];
    const float* gamma_n = (const float*)d_in[10];
    const float* beta_n  = (const float*)d_in[11];
    const float* gamma_g = (const float*)d_in[12];
    const float* beta_g  = (const float*)d_in[13];

    char* ws = (char*)d_ws;               // ~28 MB used (ws is ~512 MB)
    float*    f1      = (float*)(ws + 0);
    float*    f2      = (float*)(ws + 131072);
    float*    ecol    = (float*)(ws + 262144);
    float*    base    = (float*)(ws + 393216);
    float*    bnsum   = (float*)(ws + 524288);
    float*    bnsumsq = (float*)(ws + 524544);
    u64*      maskp   = (u64*)  (ws + 525312);      // 4 MB
    ushort_t* hT      = (ushort_t*)(ws + 4719616);  // 4 MB bf16
    float*    psum    = (float*)(ws + 8913920);     // 8 MB (64 partials x 32K)
    __half*   outl2   = (__half*)(ws + 17302528);   // 8 MB (8 slices f16)
    float*    outpre  = (float*)(ws + 25691136);    // 2 MB

    float* out_main = (float*)d_out;
    float* out_gs   = out_main + 524288;

    (void)hipMemsetAsync(bnsum, 0, 512, stream);   // bnsum + bnsumsq
    hipLaunchKernelGGL(k_h,          dim3(256),  dim3(256), 0, stream,
                       V, gsize, gstate, Wg, W, a1, a2, hT, f1, f2);
    hipLaunchKernelGGL(k_maskcolsum, dim3(2048), dim3(256), 0, stream,
                       A, f1, f2, maskp, psum);
    hipLaunchKernelGGL(k_csum,       dim3(128),  dim3(256), 0, stream,
                       psum, f2, ecol, base);
    hipLaunchKernelGGL(k_pass2,      dim3(512),  dim3(256), 0, stream,
                       hT, maskp, f1, f2, ecol, base, outl2);
    hipLaunchKernelGGL(k_reduce,     dim3(256),  dim3(256), 0, stream,
                       outl2, bias, outpre, bnsum, bnsumsq);
    hipLaunchKernelGGL(k_bnapply,    dim3(128),  dim3(256), 0, stream,
                       outpre, bnsum, bnsumsq, gamma_n, beta_n, out_main,
                       gstate, Wg, gamma_g, beta_g, out_gs);
}